// Round 4
// baseline (178690.417 us; speedup 1.0000x reference)
//
#include <hip/hip_runtime.h>
#include <math.h>

typedef unsigned long long u64;

#define TILE 2048
#define CAP 96
#define QB 32

// ---------------------------------------------------------------- helpers
__device__ __forceinline__ u64 wave_min_u64(u64 v) {
#pragma unroll
  for (int off = 32; off; off >>= 1) {
    u64 o = __shfl_xor(v, off, 64);
    v = (o < v) ? o : v;
  }
  return v;
}

__device__ __forceinline__ float angf(float ax, float ay, float az,
                                      float bx, float by, float bz) {
  float cx = ay * bz - az * by;
  float cy = az * bx - ax * bz;
  float cz = ax * by - ay * bx;
  float cn = sqrtf(cx * cx + cy * cy + cz * cz);
  float dt = ax * bx + ay * by + az * bz;
  return atan2f(cn, dt);
}

// ---------------------------------------------------------------- lin_in
__global__ __launch_bounds__(256) void k_lin_in(
    const float* __restrict__ x, const float* __restrict__ w0,
    const float* __restrict__ b0, const float* __restrict__ w1,
    const float* __restrict__ b1, float* __restrict__ h) {
  __shared__ __align__(16) float sW0[1024];
  __shared__ __align__(16) float sW1[4096];
  __shared__ float sB0[64], sB1[64];
  for (int i = threadIdx.x; i < 1024; i += 256) sW0[i] = w0[i];
  for (int i = threadIdx.x; i < 4096; i += 256) sW1[i] = w1[i];
  if (threadIdx.x < 64) { sB0[threadIdx.x] = b0[threadIdx.x]; sB1[threadIdx.x] = b1[threadIdx.x]; }
  __syncthreads();
  int p = blockIdx.x * 256 + threadIdx.x;
  float h1[64];
#pragma unroll
  for (int o = 0; o < 64; ++o) h1[o] = sB0[o];
#pragma unroll
  for (int c4 = 0; c4 < 4; ++c4) {
    float4 xv = *(const float4*)&x[p * 16 + 4 * c4];
#pragma unroll
    for (int u = 0; u < 4; ++u) {
      float v = (u == 0) ? xv.x : (u == 1) ? xv.y : (u == 2) ? xv.z : xv.w;
      int c = 4 * c4 + u;
#pragma unroll
      for (int o4 = 0; o4 < 16; ++o4) {
        float4 w = *(const float4*)&sW0[c * 64 + 4 * o4];
        h1[4 * o4 + 0] = fmaf(v, w.x, h1[4 * o4 + 0]);
        h1[4 * o4 + 1] = fmaf(v, w.y, h1[4 * o4 + 1]);
        h1[4 * o4 + 2] = fmaf(v, w.z, h1[4 * o4 + 2]);
        h1[4 * o4 + 3] = fmaf(v, w.w, h1[4 * o4 + 3]);
      }
    }
  }
#pragma unroll
  for (int o = 0; o < 64; ++o) h1[o] = fmaxf(h1[o], 0.f);
  float h2[64];
#pragma unroll
  for (int o = 0; o < 64; ++o) h2[o] = sB1[o];
#pragma unroll
  for (int c = 0; c < 64; ++c) {
    float v = h1[c];
#pragma unroll
    for (int o4 = 0; o4 < 16; ++o4) {
      float4 w = *(const float4*)&sW1[c * 64 + 4 * o4];
      h2[4 * o4 + 0] = fmaf(v, w.x, h2[4 * o4 + 0]);
      h2[4 * o4 + 1] = fmaf(v, w.y, h2[4 * o4 + 1]);
      h2[4 * o4 + 2] = fmaf(v, w.z, h2[4 * o4 + 2]);
      h2[4 * o4 + 3] = fmaf(v, w.w, h2[4 * o4 + 3]);
    }
  }
#pragma unroll
  for (int o4 = 0; o4 < 16; ++o4) {
    float4 o;
    o.x = fmaxf(h2[4 * o4 + 0], 0.f);
    o.y = fmaxf(h2[4 * o4 + 1], 0.f);
    o.z = fmaxf(h2[4 * o4 + 2], 0.f);
    o.w = fmaxf(h2[4 * o4 + 3], 0.f);
    *(float4*)&h[(long)p * 64 + 4 * o4] = o;
  }
}

// --------------------------------------------- A = feat @ W0[:64,:] + b0
__global__ __launch_bounds__(256) void k_precompA(
    const float* __restrict__ feat, const float* __restrict__ w,
    const float* __restrict__ b, float* __restrict__ A, int n) {
  __shared__ __align__(16) float sW[4352];
  __shared__ float sB[68];
  for (int i = threadIdx.x; i < 4352; i += 256) sW[i] = w[i];
  for (int i = threadIdx.x; i < 68; i += 256) sB[i] = b[i];
  __syncthreads();
  int p = blockIdx.x * 256 + threadIdx.x;
  if (p >= n) return;
  float acc[68];
#pragma unroll
  for (int o = 0; o < 68; ++o) acc[o] = sB[o];
#pragma unroll
  for (int c4 = 0; c4 < 16; ++c4) {
    float4 f = *(const float4*)&feat[(long)p * 64 + 4 * c4];
#pragma unroll
    for (int u = 0; u < 4; ++u) {
      float v = (u == 0) ? f.x : (u == 1) ? f.y : (u == 2) ? f.z : f.w;
      int c = 4 * c4 + u;
#pragma unroll
      for (int o4 = 0; o4 < 17; ++o4) {
        float4 wv = *(const float4*)&sW[c * 68 + 4 * o4];
        acc[4 * o4 + 0] = fmaf(v, wv.x, acc[4 * o4 + 0]);
        acc[4 * o4 + 1] = fmaf(v, wv.y, acc[4 * o4 + 1]);
        acc[4 * o4 + 2] = fmaf(v, wv.z, acc[4 * o4 + 2]);
        acc[4 * o4 + 3] = fmaf(v, wv.w, acc[4 * o4 + 3]);
      }
    }
  }
#pragma unroll
  for (int o4 = 0; o4 < 17; ++o4) {
    float4 o;
    o.x = acc[4 * o4 + 0]; o.y = acc[4 * o4 + 1];
    o.z = acc[4 * o4 + 2]; o.w = acc[4 * o4 + 3];
    *(float4*)&A[(long)p * 68 + 4 * o4] = o;
  }
}

// ---------------------------------------------------------------- FPS
// Single block, NT=1024 threads, P = n/NT points per thread. xr/yr/dr in
// registers, z in LDS. __launch_bounds__(NT, 1): hipcc's 2nd arg behaves as
// CUDA min-blocks-per-CU (evidence: (512,2)->128 VGPR, (1024,4)->64 VGPR),
// so 1 block/CU of 16 waves = 4 waves/SIMD -> 128-VGPR cap. P=32 state
// (96 regs) + temps fits 128 -> no scratch spill.
// Two barriers per iteration: per-wave (val,~idx) u64 partials -> wave 0
// shuffle-reduce -> broadcast. Tie-break = smallest index (jnp.argmax).
template <int P, int NT>
__global__ __launch_bounds__(NT, 1) void k_fps(const float* __restrict__ pos,
                                               int n, int m,
                                               int* __restrict__ sel) {
#pragma clang fp contract(off)
  constexpr int NW = NT / 64;
  __shared__ float zb[NT * P];
  __shared__ u64 wk[NW];
  __shared__ int curS;
  const int t = threadIdx.x, lane = t & 63, wv = t >> 6;
  float xr[P], yr[P], dr[P];
#pragma unroll
  for (int j = 0; j < P; ++j) {
    int idx = t + NT * j;
    xr[j] = pos[3 * idx + 0];
    yr[j] = pos[3 * idx + 1];
    zb[idx] = pos[3 * idx + 2];
    dr[j] = 3.402823466e38f;
  }
  if (t == 0) sel[0] = 0;
  __syncthreads();
  int cur = 0;
  for (int i = 1; i < m; ++i) {
    float px = pos[3 * cur + 0], py = pos[3 * cur + 1], pz = pos[3 * cur + 2];
    float bv = -1.f;
    int bi = 0;
#pragma unroll
    for (int j = 0; j < P; ++j) {
      int idx = t + NT * j;
      float ax = xr[j] - px, ay = yr[j] - py, az = zb[idx] - pz;
      float d = (ax * ax + ay * ay) + az * az;
      float nd = fminf(dr[j], d);
      dr[j] = nd;
      if (nd > bv) { bv = nd; bi = idx; }
    }
#pragma unroll
    for (int off = 32; off; off >>= 1) {
      float ov = __shfl_xor(bv, off, 64);
      int oi = __shfl_xor(bi, off, 64);
      if (ov > bv || (ov == bv && oi < bi)) { bv = ov; bi = oi; }
    }
    if (lane == 0)
      wk[wv] = ((u64)__float_as_uint(bv) << 32) | (unsigned)(~bi);
    __syncthreads();   // barrier 1: wk complete (also fences prev-iter curS reads)
    if (wv == 0) {
      u64 k = (lane < NW) ? wk[lane] : 0ull;
#pragma unroll
      for (int off = NW / 2; off; off >>= 1) {
        u64 o = __shfl_xor(k, off, 64);
        if (o > k) k = o;
      }
      if (lane == 0) curS = (int)(~(unsigned)k);
    }
    __syncthreads();   // barrier 2: curS ready (also fences wave0's wk reads)
    cur = curS;
    if (t == 0) sel[i] = cur;
  }
}

// ---------------------------------------------------------------- gather
__global__ __launch_bounds__(256) void k_gather(
    const float* __restrict__ pos, const float* __restrict__ nrm,
    const int* __restrict__ sel, int m, float* __restrict__ opos,
    float* __restrict__ onrm) {
  int i = blockIdx.x * 256 + threadIdx.x;
  if (i >= m) return;
  int s = sel[i];
  opos[3 * i + 0] = pos[3 * s + 0];
  opos[3 * i + 1] = pos[3 * s + 1];
  opos[3 * i + 2] = pos[3 * s + 2];
  onrm[3 * i + 0] = nrm[3 * s + 0];
  onrm[3 * i + 1] = nrm[3 * s + 1];
  onrm[3 * i + 2] = nrm[3 * s + 2];
}

// ---------------------------------------------------------------- conv
// Per block: 32 queries. Phase 1: exact (top-32 within radius) KNN via
// threshold-filtered candidate buffers. Phase 2: m1=relu(A_j+ppf@W0p),
// m2=relu(m1@W1+b1), max over neighbors, out=relu(agg@W2+b2).
__global__ __launch_bounds__(512) void k_conv(
    const float* __restrict__ qpos, const float* __restrict__ qnorm, int nq,
    const float* __restrict__ dpos, const float* __restrict__ dnorm, int n,
    const float* __restrict__ A, const float* __restrict__ w0p,
    const float* __restrict__ w1g, const float* __restrict__ b1g,
    const float* __restrict__ w2g, const float* __restrict__ b2g, float r2,
    float* __restrict__ xout) {
  __shared__ __align__(16) float smem[12288];  // tile(6144f) + cand(3072 u64) / later W1(4624f)+W2(4352f)
  __shared__ float aggS[QB][68];
  __shared__ int knnS[QB][32];
  __shared__ float qpS[QB][3], qnS[QB][3];
  __shared__ __align__(16) float w0pS[272];  // transposed [o][f]
  __shared__ float b1S[68], b2S[64];

  const int tid = threadIdx.x, lane = tid & 63, wv = tid >> 6;
  const int q0 = blockIdx.x * QB;
  float* tileS = smem;
  u64* cand = (u64*)&smem[6144];

  for (int i = tid; i < QB * 3; i += 512) {
    ((float*)qpS)[i] = qpos[q0 * 3 + i];
    ((float*)qnS)[i] = qnorm[q0 * 3 + i];
  }
  for (int i = tid; i < 272; i += 512) {
    int o = i >> 2, f = i & 3;
    w0pS[i] = w0p[f * 68 + o];
  }
  for (int i = tid; i < 68; i += 512) b1S[i] = b1g[i];
  for (int i = tid; i < 64; i += 512) b2S[i] = b2g[i];
  __syncthreads();

  // -------- KNN: each wave owns 4 queries --------
  float qx[4], qy[4], qz[4], thr[4];
  int cnt[4], tight[4];
#pragma unroll
  for (int qi = 0; qi < 4; ++qi) {
    int ql = wv * 4 + qi;
    qx[qi] = qpS[ql][0]; qy[qi] = qpS[ql][1]; qz[qi] = qpS[ql][2];
    thr[qi] = r2; cnt[qi] = 0; tight[qi] = 0;
  }
  const u64 lmask = (1ull << lane) - 1ull;
  for (int t0 = 0; t0 < n; t0 += TILE) {
    __syncthreads();
    for (int i = tid; i < TILE * 3; i += 512) tileS[i] = dpos[t0 * 3 + i];
    __syncthreads();
    for (int s = 0; s < TILE; s += 64) {
      int p = s + lane;
      float px = tileS[3 * p], py = tileS[3 * p + 1], pz = tileS[3 * p + 2];
      int gidx = t0 + p;
#pragma unroll
      for (int qi = 0; qi < 4; ++qi) {
        float d2;
        {
#pragma clang fp contract(off)
          float ax = px - qx[qi], ay = py - qy[qi], az = pz - qz[qi];
          d2 = (ax * ax + ay * ay) + az * az;
        }
        bool pred = tight[qi] ? (d2 < thr[qi]) : (d2 <= thr[qi]);
        u64 mask = __ballot(pred);
        if (mask) {
          int need = __popcll(mask);
          int base = (wv * 4 + qi) * CAP;
          if (cnt[qi] + need > CAP) {  // compact to 32 smallest, tighten thr
            u64 v0 = (lane < cnt[qi]) ? cand[base + lane] : ~0ull;
            u64 v1 = (lane + 64 < cnt[qi]) ? cand[base + lane + 64] : ~0ull;
            u64 keep = ~0ull, last = 0;
            for (int it = 0; it < 32; ++it) {
              u64 mloc = (v0 < v1) ? v0 : v1;
              u64 mn = wave_min_u64(mloc);
              if (lane == it) keep = mn;
              if (v0 == mn) v0 = ~0ull; else if (v1 == mn) v1 = ~0ull;
              last = mn;
            }
            if (lane < 32) cand[base + lane] = keep;
            cnt[qi] = 32;
            thr[qi] = __uint_as_float((unsigned)(last >> 32));
            tight[qi] = 1;
          }
          if (pred) {
            int slot = cnt[qi] + __popcll(mask & lmask);
            cand[base + slot] = ((u64)__float_as_uint(d2) << 32) | (unsigned)gidx;
          }
          cnt[qi] += need;
        }
      }
    }
  }
  // final exact selection (ascending (d2, idx)); pad with neighbor 0 (self)
#pragma unroll
  for (int qi = 0; qi < 4; ++qi) {
    int ql = wv * 4 + qi, base = ql * CAP, c = cnt[qi];
    int nout = (c < 32) ? c : 32;
    u64 v0 = (lane < c) ? cand[base + lane] : ~0ull;
    u64 v1 = (lane + 64 < c) ? cand[base + lane + 64] : ~0ull;
    int first = 0;
    for (int it = 0; it < 32; ++it) {
      u64 mloc = (v0 < v1) ? v0 : v1;
      u64 mn = wave_min_u64(mloc);
      int idx = (int)(mn & 0xffffffffu);
      if (it == 0) first = idx;
      int wr = (it < nout) ? idx : first;
      if (lane == it) knnS[ql][it] = wr;
      if (it < nout) {
        if (v0 == mn) v0 = ~0ull; else if (v1 == mn) v1 = ~0ull;
      }
    }
  }
  __syncthreads();
  for (int i = tid; i < 4624; i += 512) smem[i] = w1g[i];
  for (int i = tid; i < 4352; i += 512) smem[4624 + i] = w2g[i];
  __syncthreads();
  const float* W1s = smem;
  const float* W2s = smem + 4624;

  // -------- message MLP + max-agg: wave = 2 queries, lane = (query-half, k)
#pragma unroll 1
  for (int r = 0; r < 2; ++r) {
    const int h = lane >> 5;
    const int ql = r * 16 + wv * 2 + h;
    const int kk = lane & 31;
    const int j = knnS[ql][kk];
    const float qx_ = qpS[ql][0], qy_ = qpS[ql][1], qz_ = qpS[ql][2];
    float dx = dpos[3 * j + 0] - qx_;
    float dy = dpos[3 * j + 1] - qy_;
    float dz = dpos[3 * j + 2] - qz_;
    float f0 = sqrtf(dx * dx + dy * dy + dz * dz);
    float nix = qnS[ql][0], niy = qnS[ql][1], niz = qnS[ql][2];
    float njx = dnorm[3 * j + 0], njy = dnorm[3 * j + 1], njz = dnorm[3 * j + 2];
    float f1 = angf(nix, niy, niz, dx, dy, dz);
    float f2 = angf(njx, njy, njz, dx, dy, dz);
    float f3 = angf(nix, niy, niz, njx, njy, njz);
    const float* Arow = A + (long)j * 68;
    float m1[68];
#pragma unroll
    for (int o4 = 0; o4 < 17; ++o4) {
      float4 a = *(const float4*)&Arow[4 * o4];
#pragma unroll
      for (int u = 0; u < 4; ++u) {
        int o = 4 * o4 + u;
        float4 wf = *(const float4*)&w0pS[4 * o];
        float v = (u == 0) ? a.x : (u == 1) ? a.y : (u == 2) ? a.z : a.w;
        v = fmaf(f0, wf.x, v);
        v = fmaf(f1, wf.y, v);
        v = fmaf(f2, wf.z, v);
        v = fmaf(f3, wf.w, v);
        m1[o] = fmaxf(v, 0.f);
      }
    }
    float acc[68];
#pragma unroll
    for (int o = 0; o < 68; ++o) acc[o] = b1S[o];
#pragma unroll
    for (int c = 0; c < 68; ++c) {
      float mv = m1[c];
#pragma unroll
      for (int o4 = 0; o4 < 17; ++o4) {
        float4 wv4 = *(const float4*)&W1s[c * 68 + 4 * o4];
        acc[4 * o4 + 0] = fmaf(mv, wv4.x, acc[4 * o4 + 0]);
        acc[4 * o4 + 1] = fmaf(mv, wv4.y, acc[4 * o4 + 1]);
        acc[4 * o4 + 2] = fmaf(mv, wv4.z, acc[4 * o4 + 2]);
        acc[4 * o4 + 3] = fmaf(mv, wv4.w, acc[4 * o4 + 3]);
      }
    }
#pragma unroll
    for (int o = 0; o < 68; ++o) {
      float v = fmaxf(acc[o], 0.f);
#pragma unroll
      for (int off = 16; off; off >>= 1) v = fmaxf(v, __shfl_xor(v, off, 64));
      if (kk == 0) aggS[ql][o] = v;
    }
  }
  __syncthreads();
  // -------- nn2: out = relu(agg @ W2 + b2)
  {
    const int ql = tid >> 4;
    const int og = (tid & 15) * 4;
    float a0 = b2S[og + 0], a1 = b2S[og + 1], a2 = b2S[og + 2], a3 = b2S[og + 3];
#pragma unroll
    for (int c = 0; c < 68; ++c) {
      float av = aggS[ql][c];
      float4 wv4 = *(const float4*)&W2s[c * 64 + og];
      a0 = fmaf(av, wv4.x, a0);
      a1 = fmaf(av, wv4.y, a1);
      a2 = fmaf(av, wv4.z, a2);
      a3 = fmaf(av, wv4.w, a3);
    }
    float4 o;
    o.x = fmaxf(a0, 0.f); o.y = fmaxf(a1, 0.f);
    o.z = fmaxf(a2, 0.f); o.w = fmaxf(a3, 0.f);
    *(float4*)&xout[(long)(q0 + ql) * 64 + og] = o;
  }
}

// ---------------------------------------------------------------- final
__global__ __launch_bounds__(256) void k_final(
    const float* __restrict__ x3, const float* __restrict__ w0,
    const float* __restrict__ b0, const float* __restrict__ w1,
    const float* __restrict__ b1, float* __restrict__ out) {
  __shared__ float part[4][64];
  __shared__ float pooled[64];
  __shared__ float hS[64];
  int t = threadIdx.x, c = t & 63, g = t >> 6;
  float s = 0.f;
  for (int i = g; i < 4096; i += 4) s += x3[(long)i * 64 + c];
  part[g][c] = s;
  __syncthreads();
  if (t < 64)
    pooled[t] = (part[0][t] + part[1][t] + part[2][t] + part[3][t]) * (1.f / 4096.f);
  __syncthreads();
  if (t < 64) {
    float a = b0[t];
    for (int cc = 0; cc < 64; ++cc) a = fmaf(pooled[cc], w0[cc * 64 + t], a);
    hS[t] = fmaxf(a, 0.f);
  }
  __syncthreads();
  if (t < 2) {
    float a = b1[t];
    for (int cc = 0; cc < 64; ++cc) a = fmaf(hS[cc], w1[cc * 2 + t], a);
    out[t] = a;
  }
}

// ---------------------------------------------------------------- launch
extern "C" void kernel_launch(void* const* d_in, const int* in_sizes, int n_in,
                              void* d_out, int out_size, void* d_ws,
                              size_t ws_size, hipStream_t stream) {
  (void)in_sizes; (void)n_in; (void)out_size;
  const float* x     = (const float*)d_in[0];
  const float* pos   = (const float*)d_in[1];
  const float* nrm   = (const float*)d_in[2];
  const float* li_w0 = (const float*)d_in[3];
  const float* li_b0 = (const float*)d_in[4];
  const float* li_w1 = (const float*)d_in[5];
  const float* li_b1 = (const float*)d_in[6];
  const float* n1w0  = (const float*)d_in[7];   // [3][68][68]
  const float* n1b0  = (const float*)d_in[8];   // [3][68]
  const float* n1w1  = (const float*)d_in[9];   // [3][68][68]
  const float* n1b1  = (const float*)d_in[10];  // [3][68]
  const float* n2w   = (const float*)d_in[11];  // [3][68][64]
  const float* n2b   = (const float*)d_in[12];  // [3][64]
  const float* lo_w0 = (const float*)d_in[13];
  const float* lo_b0 = (const float*)d_in[14];
  const float* lo_w1 = (const float*)d_in[15];
  const float* lo_b1 = (const float*)d_in[16];
  float* out = (float*)d_out;

  char* ws = (char*)d_ws;
  size_t off = 0;
  auto alloc = [&](size_t nb) -> void* {
    void* p = (void*)(ws + off);
    off += nb;
    off = (off + 1023) & ~((size_t)1023);
    return p;
  };
  float* h    = (float*)alloc((size_t)32768 * 64 * 4);
  float* A0   = (float*)alloc((size_t)32768 * 68 * 4);
  int*   sel0 = (int*)  alloc((size_t)16384 * 4);
  float* pos1 = (float*)alloc((size_t)16384 * 3 * 4);
  float* nrm1 = (float*)alloc((size_t)16384 * 3 * 4);
  float* x1   = (float*)alloc((size_t)16384 * 64 * 4);
  float* A1   = (float*)alloc((size_t)16384 * 68 * 4);
  int*   sel1 = (int*)  alloc((size_t)8192 * 4);
  float* pos2 = (float*)alloc((size_t)8192 * 3 * 4);
  float* nrm2 = (float*)alloc((size_t)8192 * 3 * 4);
  float* x2   = (float*)alloc((size_t)8192 * 64 * 4);
  float* A2   = (float*)alloc((size_t)8192 * 68 * 4);
  int*   sel2 = (int*)  alloc((size_t)4096 * 4);
  float* pos3 = (float*)alloc((size_t)4096 * 3 * 4);
  float* nrm3 = (float*)alloc((size_t)4096 * 3 * 4);
  float* x3   = (float*)alloc((size_t)4096 * 64 * 4);
  if (off > ws_size) return;  // workspace too small -> visible failure

  k_lin_in<<<128, 256, 0, stream>>>(x, li_w0, li_b0, li_w1, li_b1, h);
  k_precompA<<<128, 256, 0, stream>>>(h, n1w0, n1b0, A0, 32768);
  k_fps<32, 1024><<<1, 1024, 0, stream>>>(pos, 32768, 16384, sel0);
  k_gather<<<64, 256, 0, stream>>>(pos, nrm, sel0, 16384, pos1, nrm1);
  k_conv<<<512, 512, 0, stream>>>(pos1, nrm1, 16384, pos, nrm, 32768, A0,
                                  n1w0 + 64 * 68, n1w1, n1b1, n2w, n2b, 4.0f,
                                  x1);
  k_fps<16, 1024><<<1, 1024, 0, stream>>>(pos1, 16384, 8192, sel1);
  k_gather<<<32, 256, 0, stream>>>(pos1, nrm1, sel1, 8192, pos2, nrm2);
  k_precompA<<<64, 256, 0, stream>>>(x1, n1w0 + 68 * 68, n1b0 + 68, A1, 16384);
  k_conv<<<256, 512, 0, stream>>>(pos2, nrm2, 8192, pos1, nrm1, 16384, A1,
                                  n1w0 + 68 * 68 + 64 * 68, n1w1 + 68 * 68,
                                  n1b1 + 68, n2w + 68 * 64, n2b + 64, 16.0f,
                                  x2);
  k_fps<8, 1024><<<1, 1024, 0, stream>>>(pos2, 8192, 4096, sel2);
  k_gather<<<16, 256, 0, stream>>>(pos2, nrm2, sel2, 4096, pos3, nrm3);
  k_precompA<<<32, 256, 0, stream>>>(x2, n1w0 + 2 * 68 * 68, n1b0 + 2 * 68, A2,
                                     8192);
  k_conv<<<128, 512, 0, stream>>>(pos3, nrm3, 4096, pos2, nrm2, 8192, A2,
                                  n1w0 + 2 * 68 * 68 + 64 * 68,
                                  n1w1 + 2 * 68 * 68, n1b1 + 2 * 68,
                                  n2w + 2 * 68 * 64, n2b + 2 * 64, 64.0f, x3);
  k_final<<<1, 256, 0, stream>>>(x3, lo_w0, lo_b0, lo_w1, lo_b1, out);
}

// Round 5
// 177062.244 us; speedup vs baseline: 1.0092x; 1.0092x over previous
//
#include <hip/hip_runtime.h>
#include <math.h>

typedef unsigned long long u64;

#define TILE 2048
#define CAP 96
#define QB 32

// ---------------------------------------------------------------- helpers
__device__ __forceinline__ u64 wave_min_u64(u64 v) {
#pragma unroll
  for (int off = 32; off; off >>= 1) {
    u64 o = __shfl_xor(v, off, 64);
    v = (o < v) ? o : v;
  }
  return v;
}

__device__ __forceinline__ float angf(float ax, float ay, float az,
                                      float bx, float by, float bz) {
  float cx = ay * bz - az * by;
  float cy = az * bx - ax * bz;
  float cz = ax * by - ay * bx;
  float cn = sqrtf(cx * cx + cy * cy + cz * cz);
  float dt = ax * bx + ay * by + az * bz;
  return atan2f(cn, dt);
}

// ---------------------------------------------------------------- lin_in
__global__ __launch_bounds__(256) void k_lin_in(
    const float* __restrict__ x, const float* __restrict__ w0,
    const float* __restrict__ b0, const float* __restrict__ w1,
    const float* __restrict__ b1, float* __restrict__ h) {
  __shared__ __align__(16) float sW0[1024];
  __shared__ __align__(16) float sW1[4096];
  __shared__ float sB0[64], sB1[64];
  for (int i = threadIdx.x; i < 1024; i += 256) sW0[i] = w0[i];
  for (int i = threadIdx.x; i < 4096; i += 256) sW1[i] = w1[i];
  if (threadIdx.x < 64) { sB0[threadIdx.x] = b0[threadIdx.x]; sB1[threadIdx.x] = b1[threadIdx.x]; }
  __syncthreads();
  int p = blockIdx.x * 256 + threadIdx.x;
  float h1[64];
#pragma unroll
  for (int o = 0; o < 64; ++o) h1[o] = sB0[o];
#pragma unroll
  for (int c4 = 0; c4 < 4; ++c4) {
    float4 xv = *(const float4*)&x[p * 16 + 4 * c4];
#pragma unroll
    for (int u = 0; u < 4; ++u) {
      float v = (u == 0) ? xv.x : (u == 1) ? xv.y : (u == 2) ? xv.z : xv.w;
      int c = 4 * c4 + u;
#pragma unroll
      for (int o4 = 0; o4 < 16; ++o4) {
        float4 w = *(const float4*)&sW0[c * 64 + 4 * o4];
        h1[4 * o4 + 0] = fmaf(v, w.x, h1[4 * o4 + 0]);
        h1[4 * o4 + 1] = fmaf(v, w.y, h1[4 * o4 + 1]);
        h1[4 * o4 + 2] = fmaf(v, w.z, h1[4 * o4 + 2]);
        h1[4 * o4 + 3] = fmaf(v, w.w, h1[4 * o4 + 3]);
      }
    }
  }
#pragma unroll
  for (int o = 0; o < 64; ++o) h1[o] = fmaxf(h1[o], 0.f);
  float h2[64];
#pragma unroll
  for (int o = 0; o < 64; ++o) h2[o] = sB1[o];
#pragma unroll
  for (int c = 0; c < 64; ++c) {
    float v = h1[c];
#pragma unroll
    for (int o4 = 0; o4 < 16; ++o4) {
      float4 w = *(const float4*)&sW1[c * 64 + 4 * o4];
      h2[4 * o4 + 0] = fmaf(v, w.x, h2[4 * o4 + 0]);
      h2[4 * o4 + 1] = fmaf(v, w.y, h2[4 * o4 + 1]);
      h2[4 * o4 + 2] = fmaf(v, w.z, h2[4 * o4 + 2]);
      h2[4 * o4 + 3] = fmaf(v, w.w, h2[4 * o4 + 3]);
    }
  }
#pragma unroll
  for (int o4 = 0; o4 < 16; ++o4) {
    float4 o;
    o.x = fmaxf(h2[4 * o4 + 0], 0.f);
    o.y = fmaxf(h2[4 * o4 + 1], 0.f);
    o.z = fmaxf(h2[4 * o4 + 2], 0.f);
    o.w = fmaxf(h2[4 * o4 + 3], 0.f);
    *(float4*)&h[(long)p * 64 + 4 * o4] = o;
  }
}

// --------------------------------------------- A = feat @ W0[:64,:] + b0
__global__ __launch_bounds__(256) void k_precompA(
    const float* __restrict__ feat, const float* __restrict__ w,
    const float* __restrict__ b, float* __restrict__ A, int n) {
  __shared__ __align__(16) float sW[4352];
  __shared__ float sB[68];
  for (int i = threadIdx.x; i < 4352; i += 256) sW[i] = w[i];
  for (int i = threadIdx.x; i < 68; i += 256) sB[i] = b[i];
  __syncthreads();
  int p = blockIdx.x * 256 + threadIdx.x;
  if (p >= n) return;
  float acc[68];
#pragma unroll
  for (int o = 0; o < 68; ++o) acc[o] = sB[o];
#pragma unroll
  for (int c4 = 0; c4 < 16; ++c4) {
    float4 f = *(const float4*)&feat[(long)p * 64 + 4 * c4];
#pragma unroll
    for (int u = 0; u < 4; ++u) {
      float v = (u == 0) ? f.x : (u == 1) ? f.y : (u == 2) ? f.z : f.w;
      int c = 4 * c4 + u;
#pragma unroll
      for (int o4 = 0; o4 < 17; ++o4) {
        float4 wv = *(const float4*)&sW[c * 68 + 4 * o4];
        acc[4 * o4 + 0] = fmaf(v, wv.x, acc[4 * o4 + 0]);
        acc[4 * o4 + 1] = fmaf(v, wv.y, acc[4 * o4 + 1]);
        acc[4 * o4 + 2] = fmaf(v, wv.z, acc[4 * o4 + 2]);
        acc[4 * o4 + 3] = fmaf(v, wv.w, acc[4 * o4 + 3]);
      }
    }
  }
#pragma unroll
  for (int o4 = 0; o4 < 17; ++o4) {
    float4 o;
    o.x = acc[4 * o4 + 0]; o.y = acc[4 * o4 + 1];
    o.z = acc[4 * o4 + 2]; o.w = acc[4 * o4 + 3];
    *(float4*)&A[(long)p * 68 + 4 * o4] = o;
  }
}

// ---------------------------------------------------------------- FPS
// Single block, NT=1024 threads, P = n/NT points per thread. xr/yr/dr in
// registers, z in LDS.
// Register-budget note: hipcc's allocator targets 2 workgroups/CU by
// default (evidence: (512)->128, (512,2)->128, (1024,4)->64, (1024,1)->64
// VGPRs) and __launch_bounds__' 2nd arg can only RAISE occupancy. To lower
// the target to 1 block (4 waves/EU for 1024 threads) and unlock the
// 128-VGPR budget that fits xr/yr/dr (96) + temps without scratch spill,
// pin occupancy explicitly with amdgpu_waves_per_eu(4,4).
// Two barriers per iteration: per-wave (val,~idx) u64 partials -> wave 0
// shuffle-reduce -> broadcast. Tie-break = smallest index (jnp.argmax).
template <int P, int NT>
__global__ __launch_bounds__(NT)
__attribute__((amdgpu_waves_per_eu(4, 4)))
void k_fps(const float* __restrict__ pos, int n, int m,
           int* __restrict__ sel) {
#pragma clang fp contract(off)
  constexpr int NW = NT / 64;
  __shared__ float zb[NT * P];
  __shared__ u64 wk[NW];
  __shared__ int curS;
  const int t = threadIdx.x, lane = t & 63, wv = t >> 6;
  float xr[P], yr[P], dr[P];
#pragma unroll
  for (int j = 0; j < P; ++j) {
    int idx = t + NT * j;
    xr[j] = pos[3 * idx + 0];
    yr[j] = pos[3 * idx + 1];
    zb[idx] = pos[3 * idx + 2];
    dr[j] = 3.402823466e38f;
  }
  if (t == 0) sel[0] = 0;
  __syncthreads();
  int cur = 0;
  for (int i = 1; i < m; ++i) {
    float px = pos[3 * cur + 0], py = pos[3 * cur + 1], pz = pos[3 * cur + 2];
    float bv = -1.f;
    int bi = 0;
#pragma unroll
    for (int j = 0; j < P; ++j) {
      int idx = t + NT * j;
      float ax = xr[j] - px, ay = yr[j] - py, az = zb[idx] - pz;
      float d = (ax * ax + ay * ay) + az * az;
      float nd = fminf(dr[j], d);
      dr[j] = nd;
      if (nd > bv) { bv = nd; bi = idx; }
    }
#pragma unroll
    for (int off = 32; off; off >>= 1) {
      float ov = __shfl_xor(bv, off, 64);
      int oi = __shfl_xor(bi, off, 64);
      if (ov > bv || (ov == bv && oi < bi)) { bv = ov; bi = oi; }
    }
    if (lane == 0)
      wk[wv] = ((u64)__float_as_uint(bv) << 32) | (unsigned)(~bi);
    __syncthreads();   // barrier 1: wk complete (also fences prev-iter curS reads)
    if (wv == 0) {
      u64 k = (lane < NW) ? wk[lane] : 0ull;
#pragma unroll
      for (int off = NW / 2; off; off >>= 1) {
        u64 o = __shfl_xor(k, off, 64);
        if (o > k) k = o;
      }
      if (lane == 0) curS = (int)(~(unsigned)k);
    }
    __syncthreads();   // barrier 2: curS ready (also fences wave0's wk reads)
    cur = curS;
    if (t == 0) sel[i] = cur;
  }
}

// ---------------------------------------------------------------- gather
__global__ __launch_bounds__(256) void k_gather(
    const float* __restrict__ pos, const float* __restrict__ nrm,
    const int* __restrict__ sel, int m, float* __restrict__ opos,
    float* __restrict__ onrm) {
  int i = blockIdx.x * 256 + threadIdx.x;
  if (i >= m) return;
  int s = sel[i];
  opos[3 * i + 0] = pos[3 * s + 0];
  opos[3 * i + 1] = pos[3 * s + 1];
  opos[3 * i + 2] = pos[3 * s + 2];
  onrm[3 * i + 0] = nrm[3 * s + 0];
  onrm[3 * i + 1] = nrm[3 * s + 1];
  onrm[3 * i + 2] = nrm[3 * s + 2];
}

// ---------------------------------------------------------------- conv
// Per block: 32 queries. Phase 1: exact (top-32 within radius) KNN via
// threshold-filtered candidate buffers. Phase 2: m1=relu(A_j+ppf@W0p),
// m2=relu(m1@W1+b1), max over neighbors, out=relu(agg@W2+b2).
__global__ __launch_bounds__(512) void k_conv(
    const float* __restrict__ qpos, const float* __restrict__ qnorm, int nq,
    const float* __restrict__ dpos, const float* __restrict__ dnorm, int n,
    const float* __restrict__ A, const float* __restrict__ w0p,
    const float* __restrict__ w1g, const float* __restrict__ b1g,
    const float* __restrict__ w2g, const float* __restrict__ b2g, float r2,
    float* __restrict__ xout) {
  __shared__ __align__(16) float smem[12288];  // tile(6144f) + cand(3072 u64) / later W1(4624f)+W2(4352f)
  __shared__ float aggS[QB][68];
  __shared__ int knnS[QB][32];
  __shared__ float qpS[QB][3], qnS[QB][3];
  __shared__ __align__(16) float w0pS[272];  // transposed [o][f]
  __shared__ float b1S[68], b2S[64];

  const int tid = threadIdx.x, lane = tid & 63, wv = tid >> 6;
  const int q0 = blockIdx.x * QB;
  float* tileS = smem;
  u64* cand = (u64*)&smem[6144];

  for (int i = tid; i < QB * 3; i += 512) {
    ((float*)qpS)[i] = qpos[q0 * 3 + i];
    ((float*)qnS)[i] = qnorm[q0 * 3 + i];
  }
  for (int i = tid; i < 272; i += 512) {
    int o = i >> 2, f = i & 3;
    w0pS[i] = w0p[f * 68 + o];
  }
  for (int i = tid; i < 68; i += 512) b1S[i] = b1g[i];
  for (int i = tid; i < 64; i += 512) b2S[i] = b2g[i];
  __syncthreads();

  // -------- KNN: each wave owns 4 queries --------
  float qx[4], qy[4], qz[4], thr[4];
  int cnt[4], tight[4];
#pragma unroll
  for (int qi = 0; qi < 4; ++qi) {
    int ql = wv * 4 + qi;
    qx[qi] = qpS[ql][0]; qy[qi] = qpS[ql][1]; qz[qi] = qpS[ql][2];
    thr[qi] = r2; cnt[qi] = 0; tight[qi] = 0;
  }
  const u64 lmask = (1ull << lane) - 1ull;
  for (int t0 = 0; t0 < n; t0 += TILE) {
    __syncthreads();
    for (int i = tid; i < TILE * 3; i += 512) tileS[i] = dpos[t0 * 3 + i];
    __syncthreads();
    for (int s = 0; s < TILE; s += 64) {
      int p = s + lane;
      float px = tileS[3 * p], py = tileS[3 * p + 1], pz = tileS[3 * p + 2];
      int gidx = t0 + p;
#pragma unroll
      for (int qi = 0; qi < 4; ++qi) {
        float d2;
        {
#pragma clang fp contract(off)
          float ax = px - qx[qi], ay = py - qy[qi], az = pz - qz[qi];
          d2 = (ax * ax + ay * ay) + az * az;
        }
        bool pred = tight[qi] ? (d2 < thr[qi]) : (d2 <= thr[qi]);
        u64 mask = __ballot(pred);
        if (mask) {
          int need = __popcll(mask);
          int base = (wv * 4 + qi) * CAP;
          if (cnt[qi] + need > CAP) {  // compact to 32 smallest, tighten thr
            u64 v0 = (lane < cnt[qi]) ? cand[base + lane] : ~0ull;
            u64 v1 = (lane + 64 < cnt[qi]) ? cand[base + lane + 64] : ~0ull;
            u64 keep = ~0ull, last = 0;
            for (int it = 0; it < 32; ++it) {
              u64 mloc = (v0 < v1) ? v0 : v1;
              u64 mn = wave_min_u64(mloc);
              if (lane == it) keep = mn;
              if (v0 == mn) v0 = ~0ull; else if (v1 == mn) v1 = ~0ull;
              last = mn;
            }
            if (lane < 32) cand[base + lane] = keep;
            cnt[qi] = 32;
            thr[qi] = __uint_as_float((unsigned)(last >> 32));
            tight[qi] = 1;
          }
          if (pred) {
            int slot = cnt[qi] + __popcll(mask & lmask);
            cand[base + slot] = ((u64)__float_as_uint(d2) << 32) | (unsigned)gidx;
          }
          cnt[qi] += need;
        }
      }
    }
  }
  // final exact selection (ascending (d2, idx)); pad with neighbor 0 (self)
#pragma unroll
  for (int qi = 0; qi < 4; ++qi) {
    int ql = wv * 4 + qi, base = ql * CAP, c = cnt[qi];
    int nout = (c < 32) ? c : 32;
    u64 v0 = (lane < c) ? cand[base + lane] : ~0ull;
    u64 v1 = (lane + 64 < c) ? cand[base + lane + 64] : ~0ull;
    int first = 0;
    for (int it = 0; it < 32; ++it) {
      u64 mloc = (v0 < v1) ? v0 : v1;
      u64 mn = wave_min_u64(mloc);
      int idx = (int)(mn & 0xffffffffu);
      if (it == 0) first = idx;
      int wr = (it < nout) ? idx : first;
      if (lane == it) knnS[ql][it] = wr;
      if (it < nout) {
        if (v0 == mn) v0 = ~0ull; else if (v1 == mn) v1 = ~0ull;
      }
    }
  }
  __syncthreads();
  for (int i = tid; i < 4624; i += 512) smem[i] = w1g[i];
  for (int i = tid; i < 4352; i += 512) smem[4624 + i] = w2g[i];
  __syncthreads();
  const float* W1s = smem;
  const float* W2s = smem + 4624;

  // -------- message MLP + max-agg: wave = 2 queries, lane = (query-half, k)
#pragma unroll 1
  for (int r = 0; r < 2; ++r) {
    const int h = lane >> 5;
    const int ql = r * 16 + wv * 2 + h;
    const int kk = lane & 31;
    const int j = knnS[ql][kk];
    const float qx_ = qpS[ql][0], qy_ = qpS[ql][1], qz_ = qpS[ql][2];
    float dx = dpos[3 * j + 0] - qx_;
    float dy = dpos[3 * j + 1] - qy_;
    float dz = dpos[3 * j + 2] - qz_;
    float f0 = sqrtf(dx * dx + dy * dy + dz * dz);
    float nix = qnS[ql][0], niy = qnS[ql][1], niz = qnS[ql][2];
    float njx = dnorm[3 * j + 0], njy = dnorm[3 * j + 1], njz = dnorm[3 * j + 2];
    float f1 = angf(nix, niy, niz, dx, dy, dz);
    float f2 = angf(njx, njy, njz, dx, dy, dz);
    float f3 = angf(nix, niy, niz, njx, njy, njz);
    const float* Arow = A + (long)j * 68;
    float m1[68];
#pragma unroll
    for (int o4 = 0; o4 < 17; ++o4) {
      float4 a = *(const float4*)&Arow[4 * o4];
#pragma unroll
      for (int u = 0; u < 4; ++u) {
        int o = 4 * o4 + u;
        float4 wf = *(const float4*)&w0pS[4 * o];
        float v = (u == 0) ? a.x : (u == 1) ? a.y : (u == 2) ? a.z : a.w;
        v = fmaf(f0, wf.x, v);
        v = fmaf(f1, wf.y, v);
        v = fmaf(f2, wf.z, v);
        v = fmaf(f3, wf.w, v);
        m1[o] = fmaxf(v, 0.f);
      }
    }
    float acc[68];
#pragma unroll
    for (int o = 0; o < 68; ++o) acc[o] = b1S[o];
#pragma unroll
    for (int c = 0; c < 68; ++c) {
      float mv = m1[c];
#pragma unroll
      for (int o4 = 0; o4 < 17; ++o4) {
        float4 wv4 = *(const float4*)&W1s[c * 68 + 4 * o4];
        acc[4 * o4 + 0] = fmaf(mv, wv4.x, acc[4 * o4 + 0]);
        acc[4 * o4 + 1] = fmaf(mv, wv4.y, acc[4 * o4 + 1]);
        acc[4 * o4 + 2] = fmaf(mv, wv4.z, acc[4 * o4 + 2]);
        acc[4 * o4 + 3] = fmaf(mv, wv4.w, acc[4 * o4 + 3]);
      }
    }
#pragma unroll
    for (int o = 0; o < 68; ++o) {
      float v = fmaxf(acc[o], 0.f);
#pragma unroll
      for (int off = 16; off; off >>= 1) v = fmaxf(v, __shfl_xor(v, off, 64));
      if (kk == 0) aggS[ql][o] = v;
    }
  }
  __syncthreads();
  // -------- nn2: out = relu(agg @ W2 + b2)
  {
    const int ql = tid >> 4;
    const int og = (tid & 15) * 4;
    float a0 = b2S[og + 0], a1 = b2S[og + 1], a2 = b2S[og + 2], a3 = b2S[og + 3];
#pragma unroll
    for (int c = 0; c < 68; ++c) {
      float av = aggS[ql][c];
      float4 wv4 = *(const float4*)&W2s[c * 64 + og];
      a0 = fmaf(av, wv4.x, a0);
      a1 = fmaf(av, wv4.y, a1);
      a2 = fmaf(av, wv4.z, a2);
      a3 = fmaf(av, wv4.w, a3);
    }
    float4 o;
    o.x = fmaxf(a0, 0.f); o.y = fmaxf(a1, 0.f);
    o.z = fmaxf(a2, 0.f); o.w = fmaxf(a3, 0.f);
    *(float4*)&xout[(long)(q0 + ql) * 64 + og] = o;
  }
}

// ---------------------------------------------------------------- final
__global__ __launch_bounds__(256) void k_final(
    const float* __restrict__ x3, const float* __restrict__ w0,
    const float* __restrict__ b0, const float* __restrict__ w1,
    const float* __restrict__ b1, float* __restrict__ out) {
  __shared__ float part[4][64];
  __shared__ float pooled[64];
  __shared__ float hS[64];
  int t = threadIdx.x, c = t & 63, g = t >> 6;
  float s = 0.f;
  for (int i = g; i < 4096; i += 4) s += x3[(long)i * 64 + c];
  part[g][c] = s;
  __syncthreads();
  if (t < 64)
    pooled[t] = (part[0][t] + part[1][t] + part[2][t] + part[3][t]) * (1.f / 4096.f);
  __syncthreads();
  if (t < 64) {
    float a = b0[t];
    for (int cc = 0; cc < 64; ++cc) a = fmaf(pooled[cc], w0[cc * 64 + t], a);
    hS[t] = fmaxf(a, 0.f);
  }
  __syncthreads();
  if (t < 2) {
    float a = b1[t];
    for (int cc = 0; cc < 64; ++cc) a = fmaf(hS[cc], w1[cc * 2 + t], a);
    out[t] = a;
  }
}

// ---------------------------------------------------------------- launch
extern "C" void kernel_launch(void* const* d_in, const int* in_sizes, int n_in,
                              void* d_out, int out_size, void* d_ws,
                              size_t ws_size, hipStream_t stream) {
  (void)in_sizes; (void)n_in; (void)out_size;
  const float* x     = (const float*)d_in[0];
  const float* pos   = (const float*)d_in[1];
  const float* nrm   = (const float*)d_in[2];
  const float* li_w0 = (const float*)d_in[3];
  const float* li_b0 = (const float*)d_in[4];
  const float* li_w1 = (const float*)d_in[5];
  const float* li_b1 = (const float*)d_in[6];
  const float* n1w0  = (const float*)d_in[7];   // [3][68][68]
  const float* n1b0  = (const float*)d_in[8];   // [3][68]
  const float* n1w1  = (const float*)d_in[9];   // [3][68][68]
  const float* n1b1  = (const float*)d_in[10];  // [3][68]
  const float* n2w   = (const float*)d_in[11];  // [3][68][64]
  const float* n2b   = (const float*)d_in[12];  // [3][64]
  const float* lo_w0 = (const float*)d_in[13];
  const float* lo_b0 = (const float*)d_in[14];
  const float* lo_w1 = (const float*)d_in[15];
  const float* lo_b1 = (const float*)d_in[16];
  float* out = (float*)d_out;

  char* ws = (char*)d_ws;
  size_t off = 0;
  auto alloc = [&](size_t nb) -> void* {
    void* p = (void*)(ws + off);
    off += nb;
    off = (off + 1023) & ~((size_t)1023);
    return p;
  };
  float* h    = (float*)alloc((size_t)32768 * 64 * 4);
  float* A0   = (float*)alloc((size_t)32768 * 68 * 4);
  int*   sel0 = (int*)  alloc((size_t)16384 * 4);
  float* pos1 = (float*)alloc((size_t)16384 * 3 * 4);
  float* nrm1 = (float*)alloc((size_t)16384 * 3 * 4);
  float* x1   = (float*)alloc((size_t)16384 * 64 * 4);
  float* A1   = (float*)alloc((size_t)16384 * 68 * 4);
  int*   sel1 = (int*)  alloc((size_t)8192 * 4);
  float* pos2 = (float*)alloc((size_t)8192 * 3 * 4);
  float* nrm2 = (float*)alloc((size_t)8192 * 3 * 4);
  float* x2   = (float*)alloc((size_t)8192 * 64 * 4);
  float* A2   = (float*)alloc((size_t)8192 * 68 * 4);
  int*   sel2 = (int*)  alloc((size_t)4096 * 4);
  float* pos3 = (float*)alloc((size_t)4096 * 3 * 4);
  float* nrm3 = (float*)alloc((size_t)4096 * 3 * 4);
  float* x3   = (float*)alloc((size_t)4096 * 64 * 4);
  if (off > ws_size) return;  // workspace too small -> visible failure

  k_lin_in<<<128, 256, 0, stream>>>(x, li_w0, li_b0, li_w1, li_b1, h);
  k_precompA<<<128, 256, 0, stream>>>(h, n1w0, n1b0, A0, 32768);
  k_fps<32, 1024><<<1, 1024, 0, stream>>>(pos, 32768, 16384, sel0);
  k_gather<<<64, 256, 0, stream>>>(pos, nrm, sel0, 16384, pos1, nrm1);
  k_conv<<<512, 512, 0, stream>>>(pos1, nrm1, 16384, pos, nrm, 32768, A0,
                                  n1w0 + 64 * 68, n1w1, n1b1, n2w, n2b, 4.0f,
                                  x1);
  k_fps<16, 1024><<<1, 1024, 0, stream>>>(pos1, 16384, 8192, sel1);
  k_gather<<<32, 256, 0, stream>>>(pos1, nrm1, sel1, 8192, pos2, nrm2);
  k_precompA<<<64, 256, 0, stream>>>(x1, n1w0 + 68 * 68, n1b0 + 68, A1, 16384);
  k_conv<<<256, 512, 0, stream>>>(pos2, nrm2, 8192, pos1, nrm1, 16384, A1,
                                  n1w0 + 68 * 68 + 64 * 68, n1w1 + 68 * 68,
                                  n1b1 + 68, n2w + 68 * 64, n2b + 64, 16.0f,
                                  x2);
  k_fps<8, 1024><<<1, 1024, 0, stream>>>(pos2, 8192, 4096, sel2);
  k_gather<<<16, 256, 0, stream>>>(pos2, nrm2, sel2, 4096, pos3, nrm3);
  k_precompA<<<32, 256, 0, stream>>>(x2, n1w0 + 2 * 68 * 68, n1b0 + 2 * 68, A2,
                                     8192);
  k_conv<<<128, 512, 0, stream>>>(pos3, nrm3, 4096, pos2, nrm2, 8192, A2,
                                  n1w0 + 2 * 68 * 68 + 64 * 68,
                                  n1w1 + 2 * 68 * 68, n1b1 + 2 * 68,
                                  n2w + 2 * 68 * 64, n2b + 2 * 64, 64.0f, x3);
  k_final<<<1, 256, 0, stream>>>(x3, lo_w0, lo_b0, lo_w1, lo_b1, out);
}

// Round 6
// 173488.782 us; speedup vs baseline: 1.0300x; 1.0206x over previous
//
#include <hip/hip_runtime.h>
#include <math.h>

typedef unsigned long long u64;

#define TILE 2048
#define CAP 96
#define QB 32

// ---------------------------------------------------------------- helpers
__device__ __forceinline__ u64 wave_min_u64(u64 v) {
#pragma unroll
  for (int off = 32; off; off >>= 1) {
    u64 o = __shfl_xor(v, off, 64);
    v = (o < v) ? o : v;
  }
  return v;
}

__device__ __forceinline__ float angf(float ax, float ay, float az,
                                      float bx, float by, float bz) {
  float cx = ay * bz - az * by;
  float cy = az * bx - ax * bz;
  float cz = ax * by - ay * bx;
  float cn = sqrtf(cx * cx + cy * cy + cz * cz);
  float dt = ax * bx + ay * by + az * bz;
  return atan2f(cn, dt);
}

// ---------------------------------------------------------------- lin_in
__global__ __launch_bounds__(256) void k_lin_in(
    const float* __restrict__ x, const float* __restrict__ w0,
    const float* __restrict__ b0, const float* __restrict__ w1,
    const float* __restrict__ b1, float* __restrict__ h) {
  __shared__ __align__(16) float sW0[1024];
  __shared__ __align__(16) float sW1[4096];
  __shared__ float sB0[64], sB1[64];
  for (int i = threadIdx.x; i < 1024; i += 256) sW0[i] = w0[i];
  for (int i = threadIdx.x; i < 4096; i += 256) sW1[i] = w1[i];
  if (threadIdx.x < 64) { sB0[threadIdx.x] = b0[threadIdx.x]; sB1[threadIdx.x] = b1[threadIdx.x]; }
  __syncthreads();
  int p = blockIdx.x * 256 + threadIdx.x;
  float h1[64];
#pragma unroll
  for (int o = 0; o < 64; ++o) h1[o] = sB0[o];
#pragma unroll
  for (int c4 = 0; c4 < 4; ++c4) {
    float4 xv = *(const float4*)&x[p * 16 + 4 * c4];
#pragma unroll
    for (int u = 0; u < 4; ++u) {
      float v = (u == 0) ? xv.x : (u == 1) ? xv.y : (u == 2) ? xv.z : xv.w;
      int c = 4 * c4 + u;
#pragma unroll
      for (int o4 = 0; o4 < 16; ++o4) {
        float4 w = *(const float4*)&sW0[c * 64 + 4 * o4];
        h1[4 * o4 + 0] = fmaf(v, w.x, h1[4 * o4 + 0]);
        h1[4 * o4 + 1] = fmaf(v, w.y, h1[4 * o4 + 1]);
        h1[4 * o4 + 2] = fmaf(v, w.z, h1[4 * o4 + 2]);
        h1[4 * o4 + 3] = fmaf(v, w.w, h1[4 * o4 + 3]);
      }
    }
  }
#pragma unroll
  for (int o = 0; o < 64; ++o) h1[o] = fmaxf(h1[o], 0.f);
  float h2[64];
#pragma unroll
  for (int o = 0; o < 64; ++o) h2[o] = sB1[o];
#pragma unroll
  for (int c = 0; c < 64; ++c) {
    float v = h1[c];
#pragma unroll
    for (int o4 = 0; o4 < 16; ++o4) {
      float4 w = *(const float4*)&sW1[c * 64 + 4 * o4];
      h2[4 * o4 + 0] = fmaf(v, w.x, h2[4 * o4 + 0]);
      h2[4 * o4 + 1] = fmaf(v, w.y, h2[4 * o4 + 1]);
      h2[4 * o4 + 2] = fmaf(v, w.z, h2[4 * o4 + 2]);
      h2[4 * o4 + 3] = fmaf(v, w.w, h2[4 * o4 + 3]);
    }
  }
#pragma unroll
  for (int o4 = 0; o4 < 16; ++o4) {
    float4 o;
    o.x = fmaxf(h2[4 * o4 + 0], 0.f);
    o.y = fmaxf(h2[4 * o4 + 1], 0.f);
    o.z = fmaxf(h2[4 * o4 + 2], 0.f);
    o.w = fmaxf(h2[4 * o4 + 3], 0.f);
    *(float4*)&h[(long)p * 64 + 4 * o4] = o;
  }
}

// --------------------------------------------- A = feat @ W0[:64,:] + b0
__global__ __launch_bounds__(256) void k_precompA(
    const float* __restrict__ feat, const float* __restrict__ w,
    const float* __restrict__ b, float* __restrict__ A, int n) {
  __shared__ __align__(16) float sW[4352];
  __shared__ float sB[68];
  for (int i = threadIdx.x; i < 4352; i += 256) sW[i] = w[i];
  for (int i = threadIdx.x; i < 68; i += 256) sB[i] = b[i];
  __syncthreads();
  int p = blockIdx.x * 256 + threadIdx.x;
  if (p >= n) return;
  float acc[68];
#pragma unroll
  for (int o = 0; o < 68; ++o) acc[o] = sB[o];
#pragma unroll
  for (int c4 = 0; c4 < 16; ++c4) {
    float4 f = *(const float4*)&feat[(long)p * 64 + 4 * c4];
#pragma unroll
    for (int u = 0; u < 4; ++u) {
      float v = (u == 0) ? f.x : (u == 1) ? f.y : (u == 2) ? f.z : f.w;
      int c = 4 * c4 + u;
#pragma unroll
      for (int o4 = 0; o4 < 17; ++o4) {
        float4 wv = *(const float4*)&sW[c * 68 + 4 * o4];
        acc[4 * o4 + 0] = fmaf(v, wv.x, acc[4 * o4 + 0]);
        acc[4 * o4 + 1] = fmaf(v, wv.y, acc[4 * o4 + 1]);
        acc[4 * o4 + 2] = fmaf(v, wv.z, acc[4 * o4 + 2]);
        acc[4 * o4 + 3] = fmaf(v, wv.w, acc[4 * o4 + 3]);
      }
    }
  }
#pragma unroll
  for (int o4 = 0; o4 < 17; ++o4) {
    float4 o;
    o.x = acc[4 * o4 + 0]; o.y = acc[4 * o4 + 1];
    o.z = acc[4 * o4 + 2]; o.w = acc[4 * o4 + 3];
    *(float4*)&A[(long)p * 68 + 4 * o4] = o;
  }
}

// ---------------------------------------------------------------- pack xy
__global__ __launch_bounds__(256) void k_packxy(const float* __restrict__ pos,
                                                int n,
                                                float2* __restrict__ xy) {
  int i = blockIdx.x * 256 + threadIdx.x;
  if (i >= n) return;
  xy[i] = make_float2(pos[3 * i + 0], pos[3 * i + 1]);
}

// ---------------------------------------------------------------- FPS L0
// Streamed variant for n=32768: per-thread state = dr[64] ONLY (fits the
// 128-VGPR budget hipcc grants 512-thread kernels; the 192-reg xr/yr/dr
// version spills — measured rounds 1-5, and no launch_bounds/waves_per_eu
// knob raises the 1024-thread budget past 64). x/y streamed per iteration
// from packed float2 xy[] (256 KB, L2-resident); z LDS-resident.
// Single barrier/iter: parity-double-buffered per-wave (val,~idx) keys,
// every wave redundantly reduces 8 keys. Tie-break = smallest index.
template <int P>
__global__ __launch_bounds__(512) void k_fps_stream(
    const float2* __restrict__ xy, const float* __restrict__ pos, int n,
    int m, int* __restrict__ sel) {
#pragma clang fp contract(off)
  __shared__ float zb[512 * P];
  __shared__ u64 wk[2][8];
  const int t = threadIdx.x, lane = t & 63, wv = t >> 6;
  float dr[P];
#pragma unroll
  for (int j = 0; j < P; ++j) {
    int idx = t + 512 * j;
    zb[idx] = pos[3 * idx + 2];
    dr[j] = 3.402823466e38f;
  }
  if (t == 0) sel[0] = 0;
  __syncthreads();
  int cur = 0;
  for (int i = 1; i < m; ++i) {
    float2 pxy = xy[cur];          // lane-uniform dwordx2 (L2)
    float pz = zb[cur];            // LDS broadcast
    float px = pxy.x, py = pxy.y;
    float bv = -1.f;
    int bi = 0;
#pragma unroll
    for (int j = 0; j < P; ++j) {
      int idx = t + 512 * j;
      float2 v = xy[idx];
      float ax = v.x - px, ay = v.y - py, az = zb[idx] - pz;
      float d = (ax * ax + ay * ay) + az * az;
      float nd = fminf(dr[j], d);
      dr[j] = nd;
      if (nd > bv) { bv = nd; bi = idx; }
    }
#pragma unroll
    for (int off = 32; off; off >>= 1) {
      float ov = __shfl_xor(bv, off, 64);
      int oi = __shfl_xor(bi, off, 64);
      if (ov > bv || (ov == bv && oi < bi)) { bv = ov; bi = oi; }
    }
    int par = i & 1;
    if (lane == 0)
      wk[par][wv] = ((u64)__float_as_uint(bv) << 32) | (unsigned)(~bi);
    __syncthreads();
    u64 bk = wk[par][0];
#pragma unroll
    for (int w = 1; w < 8; ++w) {
      u64 o = wk[par][w];
      if (o > bk) bk = o;
    }
    cur = (int)(~(unsigned)bk);
    if (t == 0) sel[i] = cur;
  }
}

// ---------------------------------------------------------------- FPS L1/2
// Register-resident variant (P<=32): xr/yr/dr = 3P <= 96 regs fits the
// 128-VGPR budget of 512-thread kernels. z in LDS.
template <int P>
__global__ __launch_bounds__(512) void k_fps_reg(
    const float2* __restrict__ xy, const float* __restrict__ pos, int n,
    int m, int* __restrict__ sel) {
#pragma clang fp contract(off)
  __shared__ float zb[512 * P];
  __shared__ u64 wk[2][8];
  const int t = threadIdx.x, lane = t & 63, wv = t >> 6;
  float xr[P], yr[P], dr[P];
#pragma unroll
  for (int j = 0; j < P; ++j) {
    int idx = t + 512 * j;
    xr[j] = pos[3 * idx + 0];
    yr[j] = pos[3 * idx + 1];
    zb[idx] = pos[3 * idx + 2];
    dr[j] = 3.402823466e38f;
  }
  if (t == 0) sel[0] = 0;
  __syncthreads();
  int cur = 0;
  for (int i = 1; i < m; ++i) {
    float2 pxy = xy[cur];
    float pz = zb[cur];
    float px = pxy.x, py = pxy.y;
    float bv = -1.f;
    int bi = 0;
#pragma unroll
    for (int j = 0; j < P; ++j) {
      int idx = t + 512 * j;
      float ax = xr[j] - px, ay = yr[j] - py, az = zb[idx] - pz;
      float d = (ax * ax + ay * ay) + az * az;
      float nd = fminf(dr[j], d);
      dr[j] = nd;
      if (nd > bv) { bv = nd; bi = idx; }
    }
#pragma unroll
    for (int off = 32; off; off >>= 1) {
      float ov = __shfl_xor(bv, off, 64);
      int oi = __shfl_xor(bi, off, 64);
      if (ov > bv || (ov == bv && oi < bi)) { bv = ov; bi = oi; }
    }
    int par = i & 1;
    if (lane == 0)
      wk[par][wv] = ((u64)__float_as_uint(bv) << 32) | (unsigned)(~bi);
    __syncthreads();
    u64 bk = wk[par][0];
#pragma unroll
    for (int w = 1; w < 8; ++w) {
      u64 o = wk[par][w];
      if (o > bk) bk = o;
    }
    cur = (int)(~(unsigned)bk);
    if (t == 0) sel[i] = cur;
  }
}

// ---------------------------------------------------------------- gather
// Emits strided pos/norm plus packed float2 xy for the next FPS level.
__global__ __launch_bounds__(256) void k_gather(
    const float* __restrict__ pos, const float* __restrict__ nrm,
    const int* __restrict__ sel, int m, float* __restrict__ opos,
    float* __restrict__ onrm, float2* __restrict__ oxy) {
  int i = blockIdx.x * 256 + threadIdx.x;
  if (i >= m) return;
  int s = sel[i];
  float x = pos[3 * s + 0], y = pos[3 * s + 1], z = pos[3 * s + 2];
  opos[3 * i + 0] = x;
  opos[3 * i + 1] = y;
  opos[3 * i + 2] = z;
  oxy[i] = make_float2(x, y);
  onrm[3 * i + 0] = nrm[3 * s + 0];
  onrm[3 * i + 1] = nrm[3 * s + 1];
  onrm[3 * i + 2] = nrm[3 * s + 2];
}

// ---------------------------------------------------------------- conv
// Per block: 32 queries. Phase 1: exact (top-32 within radius) KNN via
// threshold-filtered candidate buffers. Phase 2: m1=relu(A_j+ppf@W0p),
// m2=relu(m1@W1+b1), max over neighbors, out=relu(agg@W2+b2).
__global__ __launch_bounds__(512) void k_conv(
    const float* __restrict__ qpos, const float* __restrict__ qnorm, int nq,
    const float* __restrict__ dpos, const float* __restrict__ dnorm, int n,
    const float* __restrict__ A, const float* __restrict__ w0p,
    const float* __restrict__ w1g, const float* __restrict__ b1g,
    const float* __restrict__ w2g, const float* __restrict__ b2g, float r2,
    float* __restrict__ xout) {
  __shared__ __align__(16) float smem[12288];  // tile(6144f) + cand(3072 u64) / later W1(4624f)+W2(4352f)
  __shared__ float aggS[QB][68];
  __shared__ int knnS[QB][32];
  __shared__ float qpS[QB][3], qnS[QB][3];
  __shared__ __align__(16) float w0pS[272];  // transposed [o][f]
  __shared__ float b1S[68], b2S[64];

  const int tid = threadIdx.x, lane = tid & 63, wv = tid >> 6;
  const int q0 = blockIdx.x * QB;
  float* tileS = smem;
  u64* cand = (u64*)&smem[6144];

  for (int i = tid; i < QB * 3; i += 512) {
    ((float*)qpS)[i] = qpos[q0 * 3 + i];
    ((float*)qnS)[i] = qnorm[q0 * 3 + i];
  }
  for (int i = tid; i < 272; i += 512) {
    int o = i >> 2, f = i & 3;
    w0pS[i] = w0p[f * 68 + o];
  }
  for (int i = tid; i < 68; i += 512) b1S[i] = b1g[i];
  for (int i = tid; i < 64; i += 512) b2S[i] = b2g[i];
  __syncthreads();

  // -------- KNN: each wave owns 4 queries --------
  float qx[4], qy[4], qz[4], thr[4];
  int cnt[4], tight[4];
#pragma unroll
  for (int qi = 0; qi < 4; ++qi) {
    int ql = wv * 4 + qi;
    qx[qi] = qpS[ql][0]; qy[qi] = qpS[ql][1]; qz[qi] = qpS[ql][2];
    thr[qi] = r2; cnt[qi] = 0; tight[qi] = 0;
  }
  const u64 lmask = (1ull << lane) - 1ull;
  for (int t0 = 0; t0 < n; t0 += TILE) {
    __syncthreads();
    for (int i = tid; i < TILE * 3; i += 512) tileS[i] = dpos[t0 * 3 + i];
    __syncthreads();
    for (int s = 0; s < TILE; s += 64) {
      int p = s + lane;
      float px = tileS[3 * p], py = tileS[3 * p + 1], pz = tileS[3 * p + 2];
      int gidx = t0 + p;
#pragma unroll
      for (int qi = 0; qi < 4; ++qi) {
        float d2;
        {
#pragma clang fp contract(off)
          float ax = px - qx[qi], ay = py - qy[qi], az = pz - qz[qi];
          d2 = (ax * ax + ay * ay) + az * az;
        }
        bool pred = tight[qi] ? (d2 < thr[qi]) : (d2 <= thr[qi]);
        u64 mask = __ballot(pred);
        if (mask) {
          int need = __popcll(mask);
          int base = (wv * 4 + qi) * CAP;
          if (cnt[qi] + need > CAP) {  // compact to 32 smallest, tighten thr
            u64 v0 = (lane < cnt[qi]) ? cand[base + lane] : ~0ull;
            u64 v1 = (lane + 64 < cnt[qi]) ? cand[base + lane + 64] : ~0ull;
            u64 keep = ~0ull, last = 0;
            for (int it = 0; it < 32; ++it) {
              u64 mloc = (v0 < v1) ? v0 : v1;
              u64 mn = wave_min_u64(mloc);
              if (lane == it) keep = mn;
              if (v0 == mn) v0 = ~0ull; else if (v1 == mn) v1 = ~0ull;
              last = mn;
            }
            if (lane < 32) cand[base + lane] = keep;
            cnt[qi] = 32;
            thr[qi] = __uint_as_float((unsigned)(last >> 32));
            tight[qi] = 1;
          }
          if (pred) {
            int slot = cnt[qi] + __popcll(mask & lmask);
            cand[base + slot] = ((u64)__float_as_uint(d2) << 32) | (unsigned)gidx;
          }
          cnt[qi] += need;
        }
      }
    }
  }
  // final exact selection (ascending (d2, idx)); pad with neighbor 0 (self)
#pragma unroll
  for (int qi = 0; qi < 4; ++qi) {
    int ql = wv * 4 + qi, base = ql * CAP, c = cnt[qi];
    int nout = (c < 32) ? c : 32;
    u64 v0 = (lane < c) ? cand[base + lane] : ~0ull;
    u64 v1 = (lane + 64 < c) ? cand[base + lane + 64] : ~0ull;
    int first = 0;
    for (int it = 0; it < 32; ++it) {
      u64 mloc = (v0 < v1) ? v0 : v1;
      u64 mn = wave_min_u64(mloc);
      int idx = (int)(mn & 0xffffffffu);
      if (it == 0) first = idx;
      int wr = (it < nout) ? idx : first;
      if (lane == it) knnS[ql][it] = wr;
      if (it < nout) {
        if (v0 == mn) v0 = ~0ull; else if (v1 == mn) v1 = ~0ull;
      }
    }
  }
  __syncthreads();
  for (int i = tid; i < 4624; i += 512) smem[i] = w1g[i];
  for (int i = tid; i < 4352; i += 512) smem[4624 + i] = w2g[i];
  __syncthreads();
  const float* W1s = smem;
  const float* W2s = smem + 4624;

  // -------- message MLP + max-agg: wave = 2 queries, lane = (query-half, k)
#pragma unroll 1
  for (int r = 0; r < 2; ++r) {
    const int h = lane >> 5;
    const int ql = r * 16 + wv * 2 + h;
    const int kk = lane & 31;
    const int j = knnS[ql][kk];
    const float qx_ = qpS[ql][0], qy_ = qpS[ql][1], qz_ = qpS[ql][2];
    float dx = dpos[3 * j + 0] - qx_;
    float dy = dpos[3 * j + 1] - qy_;
    float dz = dpos[3 * j + 2] - qz_;
    float f0 = sqrtf(dx * dx + dy * dy + dz * dz);
    float nix = qnS[ql][0], niy = qnS[ql][1], niz = qnS[ql][2];
    float njx = dnorm[3 * j + 0], njy = dnorm[3 * j + 1], njz = dnorm[3 * j + 2];
    float f1 = angf(nix, niy, niz, dx, dy, dz);
    float f2 = angf(njx, njy, njz, dx, dy, dz);
    float f3 = angf(nix, niy, niz, njx, njy, njz);
    const float* Arow = A + (long)j * 68;
    float m1[68];
#pragma unroll
    for (int o4 = 0; o4 < 17; ++o4) {
      float4 a = *(const float4*)&Arow[4 * o4];
#pragma unroll
      for (int u = 0; u < 4; ++u) {
        int o = 4 * o4 + u;
        float4 wf = *(const float4*)&w0pS[4 * o];
        float v = (u == 0) ? a.x : (u == 1) ? a.y : (u == 2) ? a.z : a.w;
        v = fmaf(f0, wf.x, v);
        v = fmaf(f1, wf.y, v);
        v = fmaf(f2, wf.z, v);
        v = fmaf(f3, wf.w, v);
        m1[o] = fmaxf(v, 0.f);
      }
    }
    float acc[68];
#pragma unroll
    for (int o = 0; o < 68; ++o) acc[o] = b1S[o];
#pragma unroll
    for (int c = 0; c < 68; ++c) {
      float mv = m1[c];
#pragma unroll
      for (int o4 = 0; o4 < 17; ++o4) {
        float4 wv4 = *(const float4*)&W1s[c * 68 + 4 * o4];
        acc[4 * o4 + 0] = fmaf(mv, wv4.x, acc[4 * o4 + 0]);
        acc[4 * o4 + 1] = fmaf(mv, wv4.y, acc[4 * o4 + 1]);
        acc[4 * o4 + 2] = fmaf(mv, wv4.z, acc[4 * o4 + 2]);
        acc[4 * o4 + 3] = fmaf(mv, wv4.w, acc[4 * o4 + 3]);
      }
    }
#pragma unroll
    for (int o = 0; o < 68; ++o) {
      float v = fmaxf(acc[o], 0.f);
#pragma unroll
      for (int off = 16; off; off >>= 1) v = fmaxf(v, __shfl_xor(v, off, 64));
      if (kk == 0) aggS[ql][o] = v;
    }
  }
  __syncthreads();
  // -------- nn2: out = relu(agg @ W2 + b2)
  {
    const int ql = tid >> 4;
    const int og = (tid & 15) * 4;
    float a0 = b2S[og + 0], a1 = b2S[og + 1], a2 = b2S[og + 2], a3 = b2S[og + 3];
#pragma unroll
    for (int c = 0; c < 68; ++c) {
      float av = aggS[ql][c];
      float4 wv4 = *(const float4*)&W2s[c * 64 + og];
      a0 = fmaf(av, wv4.x, a0);
      a1 = fmaf(av, wv4.y, a1);
      a2 = fmaf(av, wv4.z, a2);
      a3 = fmaf(av, wv4.w, a3);
    }
    float4 o;
    o.x = fmaxf(a0, 0.f); o.y = fmaxf(a1, 0.f);
    o.z = fmaxf(a2, 0.f); o.w = fmaxf(a3, 0.f);
    *(float4*)&xout[(long)(q0 + ql) * 64 + og] = o;
  }
}

// ---------------------------------------------------------------- final
__global__ __launch_bounds__(256) void k_final(
    const float* __restrict__ x3, const float* __restrict__ w0,
    const float* __restrict__ b0, const float* __restrict__ w1,
    const float* __restrict__ b1, float* __restrict__ out) {
  __shared__ float part[4][64];
  __shared__ float pooled[64];
  __shared__ float hS[64];
  int t = threadIdx.x, c = t & 63, g = t >> 6;
  float s = 0.f;
  for (int i = g; i < 4096; i += 4) s += x3[(long)i * 64 + c];
  part[g][c] = s;
  __syncthreads();
  if (t < 64)
    pooled[t] = (part[0][t] + part[1][t] + part[2][t] + part[3][t]) * (1.f / 4096.f);
  __syncthreads();
  if (t < 64) {
    float a = b0[t];
    for (int cc = 0; cc < 64; ++cc) a = fmaf(pooled[cc], w0[cc * 64 + t], a);
    hS[t] = fmaxf(a, 0.f);
  }
  __syncthreads();
  if (t < 2) {
    float a = b1[t];
    for (int cc = 0; cc < 64; ++cc) a = fmaf(hS[cc], w1[cc * 2 + t], a);
    out[t] = a;
  }
}

// ---------------------------------------------------------------- launch
extern "C" void kernel_launch(void* const* d_in, const int* in_sizes, int n_in,
                              void* d_out, int out_size, void* d_ws,
                              size_t ws_size, hipStream_t stream) {
  (void)in_sizes; (void)n_in; (void)out_size;
  const float* x     = (const float*)d_in[0];
  const float* pos   = (const float*)d_in[1];
  const float* nrm   = (const float*)d_in[2];
  const float* li_w0 = (const float*)d_in[3];
  const float* li_b0 = (const float*)d_in[4];
  const float* li_w1 = (const float*)d_in[5];
  const float* li_b1 = (const float*)d_in[6];
  const float* n1w0  = (const float*)d_in[7];   // [3][68][68]
  const float* n1b0  = (const float*)d_in[8];   // [3][68]
  const float* n1w1  = (const float*)d_in[9];   // [3][68][68]
  const float* n1b1  = (const float*)d_in[10];  // [3][68]
  const float* n2w   = (const float*)d_in[11];  // [3][68][64]
  const float* n2b   = (const float*)d_in[12];  // [3][64]
  const float* lo_w0 = (const float*)d_in[13];
  const float* lo_b0 = (const float*)d_in[14];
  const float* lo_w1 = (const float*)d_in[15];
  const float* lo_b1 = (const float*)d_in[16];
  float* out = (float*)d_out;

  char* ws = (char*)d_ws;
  size_t off = 0;
  auto alloc = [&](size_t nb) -> void* {
    void* p = (void*)(ws + off);
    off += nb;
    off = (off + 1023) & ~((size_t)1023);
    return p;
  };
  float* h    = (float*)alloc((size_t)32768 * 64 * 4);
  float* A0   = (float*)alloc((size_t)32768 * 68 * 4);
  float2* xy0 = (float2*)alloc((size_t)32768 * 8);
  int*   sel0 = (int*)  alloc((size_t)16384 * 4);
  float* pos1 = (float*)alloc((size_t)16384 * 3 * 4);
  float* nrm1 = (float*)alloc((size_t)16384 * 3 * 4);
  float2* xy1 = (float2*)alloc((size_t)16384 * 8);
  float* x1   = (float*)alloc((size_t)16384 * 64 * 4);
  float* A1   = (float*)alloc((size_t)16384 * 68 * 4);
  int*   sel1 = (int*)  alloc((size_t)8192 * 4);
  float* pos2 = (float*)alloc((size_t)8192 * 3 * 4);
  float* nrm2 = (float*)alloc((size_t)8192 * 3 * 4);
  float2* xy2 = (float2*)alloc((size_t)8192 * 8);
  float* x2   = (float*)alloc((size_t)8192 * 64 * 4);
  float* A2   = (float*)alloc((size_t)8192 * 68 * 4);
  int*   sel2 = (int*)  alloc((size_t)4096 * 4);
  float* pos3 = (float*)alloc((size_t)4096 * 3 * 4);
  float* nrm3 = (float*)alloc((size_t)4096 * 3 * 4);
  float2* xy3 = (float2*)alloc((size_t)4096 * 8);  // unused; keeps gather uniform
  float* x3   = (float*)alloc((size_t)4096 * 64 * 4);
  if (off > ws_size) return;  // workspace too small -> visible failure

  k_lin_in<<<128, 256, 0, stream>>>(x, li_w0, li_b0, li_w1, li_b1, h);
  k_precompA<<<128, 256, 0, stream>>>(h, n1w0, n1b0, A0, 32768);
  k_packxy<<<128, 256, 0, stream>>>(pos, 32768, xy0);
  k_fps_stream<64><<<1, 512, 0, stream>>>(xy0, pos, 32768, 16384, sel0);
  k_gather<<<64, 256, 0, stream>>>(pos, nrm, sel0, 16384, pos1, nrm1, xy1);
  k_conv<<<512, 512, 0, stream>>>(pos1, nrm1, 16384, pos, nrm, 32768, A0,
                                  n1w0 + 64 * 68, n1w1, n1b1, n2w, n2b, 4.0f,
                                  x1);
  k_fps_reg<32><<<1, 512, 0, stream>>>(xy1, pos1, 16384, 8192, sel1);
  k_gather<<<32, 256, 0, stream>>>(pos1, nrm1, sel1, 8192, pos2, nrm2, xy2);
  k_precompA<<<64, 256, 0, stream>>>(x1, n1w0 + 68 * 68, n1b0 + 68, A1, 16384);
  k_conv<<<256, 512, 0, stream>>>(pos2, nrm2, 8192, pos1, nrm1, 16384, A1,
                                  n1w0 + 68 * 68 + 64 * 68, n1w1 + 68 * 68,
                                  n1b1 + 68, n2w + 68 * 64, n2b + 64, 16.0f,
                                  x2);
  k_fps_reg<16><<<1, 512, 0, stream>>>(xy2, pos2, 8192, 4096, sel2);
  k_gather<<<16, 256, 0, stream>>>(pos2, nrm2, sel2, 4096, pos3, nrm3, xy3);
  k_precompA<<<32, 256, 0, stream>>>(x2, n1w0 + 2 * 68 * 68, n1b0 + 2 * 68, A2,
                                     8192);
  k_conv<<<128, 512, 0, stream>>>(pos3, nrm3, 4096, pos2, nrm2, 8192, A2,
                                  n1w0 + 2 * 68 * 68 + 64 * 68,
                                  n1w1 + 2 * 68 * 68, n1b1 + 2 * 68,
                                  n2w + 2 * 68 * 64, n2b + 2 * 64, 64.0f, x3);
  k_final<<<1, 256, 0, stream>>>(x3, lo_w0, lo_b0, lo_w1, lo_b1, out);
}

// Round 7
// 137849.060 us; speedup vs baseline: 1.2963x; 1.2585x over previous
//
#include <hip/hip_runtime.h>
#include <math.h>

typedef unsigned long long u64;

#define TILE 2048
#define CAP 96
#define QB 32

// ---------------------------------------------------------------- helpers
__device__ __forceinline__ u64 wave_min_u64(u64 v) {
#pragma unroll
  for (int off = 32; off; off >>= 1) {
    u64 o = __shfl_xor(v, off, 64);
    v = (o < v) ? o : v;
  }
  return v;
}

__device__ __forceinline__ float angf(float ax, float ay, float az,
                                      float bx, float by, float bz) {
  float cx = ay * bz - az * by;
  float cy = az * bx - ax * bz;
  float cz = ax * by - ay * bx;
  float cn = sqrtf(cx * cx + cy * cy + cz * cz);
  float dt = ax * bx + ay * by + az * bz;
  return atan2f(cn, dt);
}

// ---------------------------------------------------------------- lin_in
__global__ __launch_bounds__(256) void k_lin_in(
    const float* __restrict__ x, const float* __restrict__ w0,
    const float* __restrict__ b0, const float* __restrict__ w1,
    const float* __restrict__ b1, float* __restrict__ h) {
  __shared__ __align__(16) float sW0[1024];
  __shared__ __align__(16) float sW1[4096];
  __shared__ float sB0[64], sB1[64];
  for (int i = threadIdx.x; i < 1024; i += 256) sW0[i] = w0[i];
  for (int i = threadIdx.x; i < 4096; i += 256) sW1[i] = w1[i];
  if (threadIdx.x < 64) { sB0[threadIdx.x] = b0[threadIdx.x]; sB1[threadIdx.x] = b1[threadIdx.x]; }
  __syncthreads();
  int p = blockIdx.x * 256 + threadIdx.x;
  float h1[64];
#pragma unroll
  for (int o = 0; o < 64; ++o) h1[o] = sB0[o];
#pragma unroll
  for (int c4 = 0; c4 < 4; ++c4) {
    float4 xv = *(const float4*)&x[p * 16 + 4 * c4];
#pragma unroll
    for (int u = 0; u < 4; ++u) {
      float v = (u == 0) ? xv.x : (u == 1) ? xv.y : (u == 2) ? xv.z : xv.w;
      int c = 4 * c4 + u;
#pragma unroll
      for (int o4 = 0; o4 < 16; ++o4) {
        float4 w = *(const float4*)&sW0[c * 64 + 4 * o4];
        h1[4 * o4 + 0] = fmaf(v, w.x, h1[4 * o4 + 0]);
        h1[4 * o4 + 1] = fmaf(v, w.y, h1[4 * o4 + 1]);
        h1[4 * o4 + 2] = fmaf(v, w.z, h1[4 * o4 + 2]);
        h1[4 * o4 + 3] = fmaf(v, w.w, h1[4 * o4 + 3]);
      }
    }
  }
#pragma unroll
  for (int o = 0; o < 64; ++o) h1[o] = fmaxf(h1[o], 0.f);
  float h2[64];
#pragma unroll
  for (int o = 0; o < 64; ++o) h2[o] = sB1[o];
#pragma unroll
  for (int c = 0; c < 64; ++c) {
    float v = h1[c];
#pragma unroll
    for (int o4 = 0; o4 < 16; ++o4) {
      float4 w = *(const float4*)&sW1[c * 64 + 4 * o4];
      h2[4 * o4 + 0] = fmaf(v, w.x, h2[4 * o4 + 0]);
      h2[4 * o4 + 1] = fmaf(v, w.y, h2[4 * o4 + 1]);
      h2[4 * o4 + 2] = fmaf(v, w.z, h2[4 * o4 + 2]);
      h2[4 * o4 + 3] = fmaf(v, w.w, h2[4 * o4 + 3]);
    }
  }
#pragma unroll
  for (int o4 = 0; o4 < 16; ++o4) {
    float4 o;
    o.x = fmaxf(h2[4 * o4 + 0], 0.f);
    o.y = fmaxf(h2[4 * o4 + 1], 0.f);
    o.z = fmaxf(h2[4 * o4 + 2], 0.f);
    o.w = fmaxf(h2[4 * o4 + 3], 0.f);
    *(float4*)&h[(long)p * 64 + 4 * o4] = o;
  }
}

// --------------------------------------------- A = feat @ W0[:64,:] + b0
__global__ __launch_bounds__(256) void k_precompA(
    const float* __restrict__ feat, const float* __restrict__ w,
    const float* __restrict__ b, float* __restrict__ A, int n) {
  __shared__ __align__(16) float sW[4352];
  __shared__ float sB[68];
  for (int i = threadIdx.x; i < 4352; i += 256) sW[i] = w[i];
  for (int i = threadIdx.x; i < 68; i += 256) sB[i] = b[i];
  __syncthreads();
  int p = blockIdx.x * 256 + threadIdx.x;
  if (p >= n) return;
  float acc[68];
#pragma unroll
  for (int o = 0; o < 68; ++o) acc[o] = sB[o];
#pragma unroll
  for (int c4 = 0; c4 < 16; ++c4) {
    float4 f = *(const float4*)&feat[(long)p * 64 + 4 * c4];
#pragma unroll
    for (int u = 0; u < 4; ++u) {
      float v = (u == 0) ? f.x : (u == 1) ? f.y : (u == 2) ? f.z : f.w;
      int c = 4 * c4 + u;
#pragma unroll
      for (int o4 = 0; o4 < 17; ++o4) {
        float4 wv = *(const float4*)&sW[c * 68 + 4 * o4];
        acc[4 * o4 + 0] = fmaf(v, wv.x, acc[4 * o4 + 0]);
        acc[4 * o4 + 1] = fmaf(v, wv.y, acc[4 * o4 + 1]);
        acc[4 * o4 + 2] = fmaf(v, wv.z, acc[4 * o4 + 2]);
        acc[4 * o4 + 3] = fmaf(v, wv.w, acc[4 * o4 + 3]);
      }
    }
  }
#pragma unroll
  for (int o4 = 0; o4 < 17; ++o4) {
    float4 o;
    o.x = acc[4 * o4 + 0]; o.y = acc[4 * o4 + 1];
    o.z = acc[4 * o4 + 2]; o.w = acc[4 * o4 + 3];
    *(float4*)&A[(long)p * 68 + 4 * o4] = o;
  }
}

// ---------------------------------------------------------------- pack xy
__global__ __launch_bounds__(256) void k_packxy(const float* __restrict__ pos,
                                                int n,
                                                float2* __restrict__ xy) {
  int i = blockIdx.x * 256 + threadIdx.x;
  if (i >= n) return;
  xy[i] = make_float2(pos[3 * i + 0], pos[3 * i + 1]);
}

// ---------------------------------------------------------------- FPS L0
// Streamed variant for n=32768. Per-thread state: dr[64] (64 regs) + two
// 8-wide float2 load buffers (32 regs) <= 128-VGPR budget. z LDS-resident.
// The j-loop is software-pipelined in groups of 8: issue group g+1's eight
// independent L2 loads into the spare buffer, then process group g;
// sched_barrier(0) at each group boundary stops the compiler from either
// serializing (waitcnt per use -> ~390 cyc/j-step, the measured R1-R6
// 10.5us/iter failure mode) or hoisting all 64 loads (which would spill dr).
template <int P>
__global__ __launch_bounds__(512) void k_fps_stream(
    const float2* __restrict__ xy, const float* __restrict__ pos, int n,
    int m, int* __restrict__ sel) {
#pragma clang fp contract(off)
  static_assert(P % 8 == 0, "P multiple of 8");
  constexpr int NG = P / 8;
  __shared__ float zb[512 * P];
  __shared__ u64 wk[2][8];
  const int t = threadIdx.x, lane = t & 63, wv = t >> 6;
  float dr[P];
#pragma unroll
  for (int j = 0; j < P; ++j) {
    int idx = t + 512 * j;
    zb[idx] = pos[3 * idx + 2];
    dr[j] = 3.402823466e38f;
  }
  if (t == 0) sel[0] = 0;
  __syncthreads();
  int cur = 0;
  for (int i = 1; i < m; ++i) {
    float2 pxy = xy[cur];          // lane-uniform dwordx2 (L2)
    float pz = zb[cur];            // LDS broadcast
    float px = pxy.x, py = pxy.y;
    float bv = -1.f;
    int bi = 0;
    float2 bufA[8], bufB[8];
#pragma unroll
    for (int k = 0; k < 8; ++k) bufA[k] = xy[t + 512 * k];
#pragma unroll
    for (int g = 0; g < NG; ++g) {
      if (g + 1 < NG) {  // issue next group's loads into the spare buffer
#pragma unroll
        for (int k = 0; k < 8; ++k) {
          if (g & 1)
            bufA[k] = xy[t + 512 * (8 * (g + 1) + k)];
          else
            bufB[k] = xy[t + 512 * (8 * (g + 1) + k)];
        }
      }
#pragma unroll
      for (int k = 0; k < 8; ++k) {
        int j = 8 * g + k;
        int idx = t + 512 * j;
        float2 v = (g & 1) ? bufB[k] : bufA[k];
        float ax = v.x - px, ay = v.y - py, az = zb[idx] - pz;
        float d = (ax * ax + ay * ay) + az * az;
        float nd = fminf(dr[j], d);
        dr[j] = nd;
        if (nd > bv) { bv = nd; bi = idx; }
      }
      __builtin_amdgcn_sched_barrier(0);  // pin group pipeline structure
    }
#pragma unroll
    for (int off = 32; off; off >>= 1) {
      float ov = __shfl_xor(bv, off, 64);
      int oi = __shfl_xor(bi, off, 64);
      if (ov > bv || (ov == bv && oi < bi)) { bv = ov; bi = oi; }
    }
    int par = i & 1;
    if (lane == 0)
      wk[par][wv] = ((u64)__float_as_uint(bv) << 32) | (unsigned)(~bi);
    __syncthreads();
    u64 bk = wk[par][0];
#pragma unroll
    for (int w = 1; w < 8; ++w) {
      u64 o = wk[par][w];
      if (o > bk) bk = o;
    }
    cur = (int)(~(unsigned)bk);
    if (t == 0) sel[i] = cur;
  }
}

// ---------------------------------------------------------------- FPS L1/2
// Register-resident variant (P<=32): xr/yr/dr = 3P <= 96 regs fits the
// 128-VGPR budget of 512-thread kernels. z in LDS. Measured ~0.74 us/iter.
template <int P>
__global__ __launch_bounds__(512) void k_fps_reg(
    const float2* __restrict__ xy, const float* __restrict__ pos, int n,
    int m, int* __restrict__ sel) {
#pragma clang fp contract(off)
  __shared__ float zb[512 * P];
  __shared__ u64 wk[2][8];
  const int t = threadIdx.x, lane = t & 63, wv = t >> 6;
  float xr[P], yr[P], dr[P];
#pragma unroll
  for (int j = 0; j < P; ++j) {
    int idx = t + 512 * j;
    xr[j] = pos[3 * idx + 0];
    yr[j] = pos[3 * idx + 1];
    zb[idx] = pos[3 * idx + 2];
    dr[j] = 3.402823466e38f;
  }
  if (t == 0) sel[0] = 0;
  __syncthreads();
  int cur = 0;
  for (int i = 1; i < m; ++i) {
    float2 pxy = xy[cur];
    float pz = zb[cur];
    float px = pxy.x, py = pxy.y;
    float bv = -1.f;
    int bi = 0;
#pragma unroll
    for (int j = 0; j < P; ++j) {
      int idx = t + 512 * j;
      float ax = xr[j] - px, ay = yr[j] - py, az = zb[idx] - pz;
      float d = (ax * ax + ay * ay) + az * az;
      float nd = fminf(dr[j], d);
      dr[j] = nd;
      if (nd > bv) { bv = nd; bi = idx; }
    }
#pragma unroll
    for (int off = 32; off; off >>= 1) {
      float ov = __shfl_xor(bv, off, 64);
      int oi = __shfl_xor(bi, off, 64);
      if (ov > bv || (ov == bv && oi < bi)) { bv = ov; bi = oi; }
    }
    int par = i & 1;
    if (lane == 0)
      wk[par][wv] = ((u64)__float_as_uint(bv) << 32) | (unsigned)(~bi);
    __syncthreads();
    u64 bk = wk[par][0];
#pragma unroll
    for (int w = 1; w < 8; ++w) {
      u64 o = wk[par][w];
      if (o > bk) bk = o;
    }
    cur = (int)(~(unsigned)bk);
    if (t == 0) sel[i] = cur;
  }
}

// ---------------------------------------------------------------- gather
// Emits strided pos/norm plus packed float2 xy for the next FPS level.
__global__ __launch_bounds__(256) void k_gather(
    const float* __restrict__ pos, const float* __restrict__ nrm,
    const int* __restrict__ sel, int m, float* __restrict__ opos,
    float* __restrict__ onrm, float2* __restrict__ oxy) {
  int i = blockIdx.x * 256 + threadIdx.x;
  if (i >= m) return;
  int s = sel[i];
  float x = pos[3 * s + 0], y = pos[3 * s + 1], z = pos[3 * s + 2];
  opos[3 * i + 0] = x;
  opos[3 * i + 1] = y;
  opos[3 * i + 2] = z;
  oxy[i] = make_float2(x, y);
  onrm[3 * i + 0] = nrm[3 * s + 0];
  onrm[3 * i + 1] = nrm[3 * s + 1];
  onrm[3 * i + 2] = nrm[3 * s + 2];
}

// ---------------------------------------------------------------- conv
// Per block: 32 queries. Phase 1: exact (top-32 within radius) KNN via
// threshold-filtered candidate buffers. Phase 2: m1=relu(A_j+ppf@W0p),
// m2=relu(m1@W1+b1), max over neighbors, out=relu(agg@W2+b2).
__global__ __launch_bounds__(512) void k_conv(
    const float* __restrict__ qpos, const float* __restrict__ qnorm, int nq,
    const float* __restrict__ dpos, const float* __restrict__ dnorm, int n,
    const float* __restrict__ A, const float* __restrict__ w0p,
    const float* __restrict__ w1g, const float* __restrict__ b1g,
    const float* __restrict__ w2g, const float* __restrict__ b2g, float r2,
    float* __restrict__ xout) {
  __shared__ __align__(16) float smem[12288];  // tile(6144f) + cand(3072 u64) / later W1(4624f)+W2(4352f)
  __shared__ float aggS[QB][68];
  __shared__ int knnS[QB][32];
  __shared__ float qpS[QB][3], qnS[QB][3];
  __shared__ __align__(16) float w0pS[272];  // transposed [o][f]
  __shared__ float b1S[68], b2S[64];

  const int tid = threadIdx.x, lane = tid & 63, wv = tid >> 6;
  const int q0 = blockIdx.x * QB;
  float* tileS = smem;
  u64* cand = (u64*)&smem[6144];

  for (int i = tid; i < QB * 3; i += 512) {
    ((float*)qpS)[i] = qpos[q0 * 3 + i];
    ((float*)qnS)[i] = qnorm[q0 * 3 + i];
  }
  for (int i = tid; i < 272; i += 512) {
    int o = i >> 2, f = i & 3;
    w0pS[i] = w0p[f * 68 + o];
  }
  for (int i = tid; i < 68; i += 512) b1S[i] = b1g[i];
  for (int i = tid; i < 64; i += 512) b2S[i] = b2g[i];
  __syncthreads();

  // -------- KNN: each wave owns 4 queries --------
  float qx[4], qy[4], qz[4], thr[4];
  int cnt[4], tight[4];
#pragma unroll
  for (int qi = 0; qi < 4; ++qi) {
    int ql = wv * 4 + qi;
    qx[qi] = qpS[ql][0]; qy[qi] = qpS[ql][1]; qz[qi] = qpS[ql][2];
    thr[qi] = r2; cnt[qi] = 0; tight[qi] = 0;
  }
  const u64 lmask = (1ull << lane) - 1ull;
  for (int t0 = 0; t0 < n; t0 += TILE) {
    __syncthreads();
    for (int i = tid; i < TILE * 3; i += 512) tileS[i] = dpos[t0 * 3 + i];
    __syncthreads();
    for (int s = 0; s < TILE; s += 64) {
      int p = s + lane;
      float px = tileS[3 * p], py = tileS[3 * p + 1], pz = tileS[3 * p + 2];
      int gidx = t0 + p;
#pragma unroll
      for (int qi = 0; qi < 4; ++qi) {
        float d2;
        {
#pragma clang fp contract(off)
          float ax = px - qx[qi], ay = py - qy[qi], az = pz - qz[qi];
          d2 = (ax * ax + ay * ay) + az * az;
        }
        bool pred = tight[qi] ? (d2 < thr[qi]) : (d2 <= thr[qi]);
        u64 mask = __ballot(pred);
        if (mask) {
          int need = __popcll(mask);
          int base = (wv * 4 + qi) * CAP;
          if (cnt[qi] + need > CAP) {  // compact to 32 smallest, tighten thr
            u64 v0 = (lane < cnt[qi]) ? cand[base + lane] : ~0ull;
            u64 v1 = (lane + 64 < cnt[qi]) ? cand[base + lane + 64] : ~0ull;
            u64 keep = ~0ull, last = 0;
            for (int it = 0; it < 32; ++it) {
              u64 mloc = (v0 < v1) ? v0 : v1;
              u64 mn = wave_min_u64(mloc);
              if (lane == it) keep = mn;
              if (v0 == mn) v0 = ~0ull; else if (v1 == mn) v1 = ~0ull;
              last = mn;
            }
            if (lane < 32) cand[base + lane] = keep;
            cnt[qi] = 32;
            thr[qi] = __uint_as_float((unsigned)(last >> 32));
            tight[qi] = 1;
          }
          if (pred) {
            int slot = cnt[qi] + __popcll(mask & lmask);
            cand[base + slot] = ((u64)__float_as_uint(d2) << 32) | (unsigned)gidx;
          }
          cnt[qi] += need;
        }
      }
    }
  }
  // final exact selection (ascending (d2, idx)); pad with neighbor 0 (self)
#pragma unroll
  for (int qi = 0; qi < 4; ++qi) {
    int ql = wv * 4 + qi, base = ql * CAP, c = cnt[qi];
    int nout = (c < 32) ? c : 32;
    u64 v0 = (lane < c) ? cand[base + lane] : ~0ull;
    u64 v1 = (lane + 64 < c) ? cand[base + lane + 64] : ~0ull;
    int first = 0;
    for (int it = 0; it < 32; ++it) {
      u64 mloc = (v0 < v1) ? v0 : v1;
      u64 mn = wave_min_u64(mloc);
      int idx = (int)(mn & 0xffffffffu);
      if (it == 0) first = idx;
      int wr = (it < nout) ? idx : first;
      if (lane == it) knnS[ql][it] = wr;
      if (it < nout) {
        if (v0 == mn) v0 = ~0ull; else if (v1 == mn) v1 = ~0ull;
      }
    }
  }
  __syncthreads();
  for (int i = tid; i < 4624; i += 512) smem[i] = w1g[i];
  for (int i = tid; i < 4352; i += 512) smem[4624 + i] = w2g[i];
  __syncthreads();
  const float* W1s = smem;
  const float* W2s = smem + 4624;

  // -------- message MLP + max-agg: wave = 2 queries, lane = (query-half, k)
#pragma unroll 1
  for (int r = 0; r < 2; ++r) {
    const int h = lane >> 5;
    const int ql = r * 16 + wv * 2 + h;
    const int kk = lane & 31;
    const int j = knnS[ql][kk];
    const float qx_ = qpS[ql][0], qy_ = qpS[ql][1], qz_ = qpS[ql][2];
    float dx = dpos[3 * j + 0] - qx_;
    float dy = dpos[3 * j + 1] - qy_;
    float dz = dpos[3 * j + 2] - qz_;
    float f0 = sqrtf(dx * dx + dy * dy + dz * dz);
    float nix = qnS[ql][0], niy = qnS[ql][1], niz = qnS[ql][2];
    float njx = dnorm[3 * j + 0], njy = dnorm[3 * j + 1], njz = dnorm[3 * j + 2];
    float f1 = angf(nix, niy, niz, dx, dy, dz);
    float f2 = angf(njx, njy, njz, dx, dy, dz);
    float f3 = angf(nix, niy, niz, njx, njy, njz);
    const float* Arow = A + (long)j * 68;
    float m1[68];
#pragma unroll
    for (int o4 = 0; o4 < 17; ++o4) {
      float4 a = *(const float4*)&Arow[4 * o4];
#pragma unroll
      for (int u = 0; u < 4; ++u) {
        int o = 4 * o4 + u;
        float4 wf = *(const float4*)&w0pS[4 * o];
        float v = (u == 0) ? a.x : (u == 1) ? a.y : (u == 2) ? a.z : a.w;
        v = fmaf(f0, wf.x, v);
        v = fmaf(f1, wf.y, v);
        v = fmaf(f2, wf.z, v);
        v = fmaf(f3, wf.w, v);
        m1[o] = fmaxf(v, 0.f);
      }
    }
    float acc[68];
#pragma unroll
    for (int o = 0; o < 68; ++o) acc[o] = b1S[o];
#pragma unroll
    for (int c = 0; c < 68; ++c) {
      float mv = m1[c];
#pragma unroll
      for (int o4 = 0; o4 < 17; ++o4) {
        float4 wv4 = *(const float4*)&W1s[c * 68 + 4 * o4];
        acc[4 * o4 + 0] = fmaf(mv, wv4.x, acc[4 * o4 + 0]);
        acc[4 * o4 + 1] = fmaf(mv, wv4.y, acc[4 * o4 + 1]);
        acc[4 * o4 + 2] = fmaf(mv, wv4.z, acc[4 * o4 + 2]);
        acc[4 * o4 + 3] = fmaf(mv, wv4.w, acc[4 * o4 + 3]);
      }
    }
#pragma unroll
    for (int o = 0; o < 68; ++o) {
      float v = fmaxf(acc[o], 0.f);
#pragma unroll
      for (int off = 16; off; off >>= 1) v = fmaxf(v, __shfl_xor(v, off, 64));
      if (kk == 0) aggS[ql][o] = v;
    }
  }
  __syncthreads();
  // -------- nn2: out = relu(agg @ W2 + b2)
  {
    const int ql = tid >> 4;
    const int og = (tid & 15) * 4;
    float a0 = b2S[og + 0], a1 = b2S[og + 1], a2 = b2S[og + 2], a3 = b2S[og + 3];
#pragma unroll
    for (int c = 0; c < 68; ++c) {
      float av = aggS[ql][c];
      float4 wv4 = *(const float4*)&W2s[c * 64 + og];
      a0 = fmaf(av, wv4.x, a0);
      a1 = fmaf(av, wv4.y, a1);
      a2 = fmaf(av, wv4.z, a2);
      a3 = fmaf(av, wv4.w, a3);
    }
    float4 o;
    o.x = fmaxf(a0, 0.f); o.y = fmaxf(a1, 0.f);
    o.z = fmaxf(a2, 0.f); o.w = fmaxf(a3, 0.f);
    *(float4*)&xout[(long)(q0 + ql) * 64 + og] = o;
  }
}

// ---------------------------------------------------------------- final
__global__ __launch_bounds__(256) void k_final(
    const float* __restrict__ x3, const float* __restrict__ w0,
    const float* __restrict__ b0, const float* __restrict__ w1,
    const float* __restrict__ b1, float* __restrict__ out) {
  __shared__ float part[4][64];
  __shared__ float pooled[64];
  __shared__ float hS[64];
  int t = threadIdx.x, c = t & 63, g = t >> 6;
  float s = 0.f;
  for (int i = g; i < 4096; i += 4) s += x3[(long)i * 64 + c];
  part[g][c] = s;
  __syncthreads();
  if (t < 64)
    pooled[t] = (part[0][t] + part[1][t] + part[2][t] + part[3][t]) * (1.f / 4096.f);
  __syncthreads();
  if (t < 64) {
    float a = b0[t];
    for (int cc = 0; cc < 64; ++cc) a = fmaf(pooled[cc], w0[cc * 64 + t], a);
    hS[t] = fmaxf(a, 0.f);
  }
  __syncthreads();
  if (t < 2) {
    float a = b1[t];
    for (int cc = 0; cc < 64; ++cc) a = fmaf(hS[cc], w1[cc * 2 + t], a);
    out[t] = a;
  }
}

// ---------------------------------------------------------------- launch
extern "C" void kernel_launch(void* const* d_in, const int* in_sizes, int n_in,
                              void* d_out, int out_size, void* d_ws,
                              size_t ws_size, hipStream_t stream) {
  (void)in_sizes; (void)n_in; (void)out_size;
  const float* x     = (const float*)d_in[0];
  const float* pos   = (const float*)d_in[1];
  const float* nrm   = (const float*)d_in[2];
  const float* li_w0 = (const float*)d_in[3];
  const float* li_b0 = (const float*)d_in[4];
  const float* li_w1 = (const float*)d_in[5];
  const float* li_b1 = (const float*)d_in[6];
  const float* n1w0  = (const float*)d_in[7];   // [3][68][68]
  const float* n1b0  = (const float*)d_in[8];   // [3][68]
  const float* n1w1  = (const float*)d_in[9];   // [3][68][68]
  const float* n1b1  = (const float*)d_in[10];  // [3][68]
  const float* n2w   = (const float*)d_in[11];  // [3][68][64]
  const float* n2b   = (const float*)d_in[12];  // [3][64]
  const float* lo_w0 = (const float*)d_in[13];
  const float* lo_b0 = (const float*)d_in[14];
  const float* lo_w1 = (const float*)d_in[15];
  const float* lo_b1 = (const float*)d_in[16];
  float* out = (float*)d_out;

  char* ws = (char*)d_ws;
  size_t off = 0;
  auto alloc = [&](size_t nb) -> void* {
    void* p = (void*)(ws + off);
    off += nb;
    off = (off + 1023) & ~((size_t)1023);
    return p;
  };
  float* h    = (float*)alloc((size_t)32768 * 64 * 4);
  float* A0   = (float*)alloc((size_t)32768 * 68 * 4);
  float2* xy0 = (float2*)alloc((size_t)32768 * 8);
  int*   sel0 = (int*)  alloc((size_t)16384 * 4);
  float* pos1 = (float*)alloc((size_t)16384 * 3 * 4);
  float* nrm1 = (float*)alloc((size_t)16384 * 3 * 4);
  float2* xy1 = (float2*)alloc((size_t)16384 * 8);
  float* x1   = (float*)alloc((size_t)16384 * 64 * 4);
  float* A1   = (float*)alloc((size_t)16384 * 68 * 4);
  int*   sel1 = (int*)  alloc((size_t)8192 * 4);
  float* pos2 = (float*)alloc((size_t)8192 * 3 * 4);
  float* nrm2 = (float*)alloc((size_t)8192 * 3 * 4);
  float2* xy2 = (float2*)alloc((size_t)8192 * 8);
  float* x2   = (float*)alloc((size_t)8192 * 64 * 4);
  float* A2   = (float*)alloc((size_t)8192 * 68 * 4);
  int*   sel2 = (int*)  alloc((size_t)4096 * 4);
  float* pos3 = (float*)alloc((size_t)4096 * 3 * 4);
  float* nrm3 = (float*)alloc((size_t)4096 * 3 * 4);
  float2* xy3 = (float2*)alloc((size_t)4096 * 8);  // unused; keeps gather uniform
  float* x3   = (float*)alloc((size_t)4096 * 64 * 4);
  if (off > ws_size) return;  // workspace too small -> visible failure

  k_lin_in<<<128, 256, 0, stream>>>(x, li_w0, li_b0, li_w1, li_b1, h);
  k_precompA<<<128, 256, 0, stream>>>(h, n1w0, n1b0, A0, 32768);
  k_packxy<<<128, 256, 0, stream>>>(pos, 32768, xy0);
  k_fps_stream<64><<<1, 512, 0, stream>>>(xy0, pos, 32768, 16384, sel0);
  k_gather<<<64, 256, 0, stream>>>(pos, nrm, sel0, 16384, pos1, nrm1, xy1);
  k_conv<<<512, 512, 0, stream>>>(pos1, nrm1, 16384, pos, nrm, 32768, A0,
                                  n1w0 + 64 * 68, n1w1, n1b1, n2w, n2b, 4.0f,
                                  x1);
  k_fps_reg<32><<<1, 512, 0, stream>>>(xy1, pos1, 16384, 8192, sel1);
  k_gather<<<32, 256, 0, stream>>>(pos1, nrm1, sel1, 8192, pos2, nrm2, xy2);
  k_precompA<<<64, 256, 0, stream>>>(x1, n1w0 + 68 * 68, n1b0 + 68, A1, 16384);
  k_conv<<<256, 512, 0, stream>>>(pos2, nrm2, 8192, pos1, nrm1, 16384, A1,
                                  n1w0 + 68 * 68 + 64 * 68, n1w1 + 68 * 68,
                                  n1b1 + 68, n2w + 68 * 64, n2b + 64, 16.0f,
                                  x2);
  k_fps_reg<16><<<1, 512, 0, stream>>>(xy2, pos2, 8192, 4096, sel2);
  k_gather<<<16, 256, 0, stream>>>(pos2, nrm2, sel2, 4096, pos3, nrm3, xy3);
  k_precompA<<<32, 256, 0, stream>>>(x2, n1w0 + 2 * 68 * 68, n1b0 + 2 * 68, A2,
                                     8192);
  k_conv<<<128, 512, 0, stream>>>(pos3, nrm3, 4096, pos2, nrm2, 8192, A2,
                                  n1w0 + 2 * 68 * 68 + 64 * 68,
                                  n1w1 + 2 * 68 * 68, n1b1 + 2 * 68,
                                  n2w + 2 * 68 * 64, n2b + 2 * 64, 64.0f, x3);
  k_final<<<1, 256, 0, stream>>>(x3, lo_w0, lo_b0, lo_w1, lo_b1, out);
}

// Round 8
// 85943.262 us; speedup vs baseline: 2.0792x; 1.6040x over previous
//
#include <hip/hip_runtime.h>
#include <math.h>

typedef unsigned long long u64;

#define TILE 2048
#define CAP 96
#define QB 32

// ---------------------------------------------------------------- helpers
__device__ __forceinline__ u64 wave_min_u64(u64 v) {
#pragma unroll
  for (int off = 32; off; off >>= 1) {
    u64 o = __shfl_xor(v, off, 64);
    v = (o < v) ? o : v;
  }
  return v;
}

__device__ __forceinline__ u64 wave_max_u64(u64 v) {
#pragma unroll
  for (int off = 32; off; off >>= 1) {
    u64 o = __shfl_xor(v, off, 64);
    v = (o > v) ? o : v;
  }
  return v;
}

__device__ __forceinline__ float angf(float ax, float ay, float az,
                                      float bx, float by, float bz) {
  float cx = ay * bz - az * by;
  float cy = az * bx - ax * bz;
  float cz = ax * by - ay * bx;
  float cn = sqrtf(cx * cx + cy * cy + cz * cz);
  float dt = ax * bx + ay * by + az * bz;
  return atan2f(cn, dt);
}

// ---------------------------------------------------------------- lin_in
__global__ __launch_bounds__(256) void k_lin_in(
    const float* __restrict__ x, const float* __restrict__ w0,
    const float* __restrict__ b0, const float* __restrict__ w1,
    const float* __restrict__ b1, float* __restrict__ h) {
  __shared__ __align__(16) float sW0[1024];
  __shared__ __align__(16) float sW1[4096];
  __shared__ float sB0[64], sB1[64];
  for (int i = threadIdx.x; i < 1024; i += 256) sW0[i] = w0[i];
  for (int i = threadIdx.x; i < 4096; i += 256) sW1[i] = w1[i];
  if (threadIdx.x < 64) { sB0[threadIdx.x] = b0[threadIdx.x]; sB1[threadIdx.x] = b1[threadIdx.x]; }
  __syncthreads();
  int p = blockIdx.x * 256 + threadIdx.x;
  float h1[64];
#pragma unroll
  for (int o = 0; o < 64; ++o) h1[o] = sB0[o];
#pragma unroll
  for (int c4 = 0; c4 < 4; ++c4) {
    float4 xv = *(const float4*)&x[p * 16 + 4 * c4];
#pragma unroll
    for (int u = 0; u < 4; ++u) {
      float v = (u == 0) ? xv.x : (u == 1) ? xv.y : (u == 2) ? xv.z : xv.w;
      int c = 4 * c4 + u;
#pragma unroll
      for (int o4 = 0; o4 < 16; ++o4) {
        float4 w = *(const float4*)&sW0[c * 64 + 4 * o4];
        h1[4 * o4 + 0] = fmaf(v, w.x, h1[4 * o4 + 0]);
        h1[4 * o4 + 1] = fmaf(v, w.y, h1[4 * o4 + 1]);
        h1[4 * o4 + 2] = fmaf(v, w.z, h1[4 * o4 + 2]);
        h1[4 * o4 + 3] = fmaf(v, w.w, h1[4 * o4 + 3]);
      }
    }
  }
#pragma unroll
  for (int o = 0; o < 64; ++o) h1[o] = fmaxf(h1[o], 0.f);
  float h2[64];
#pragma unroll
  for (int o = 0; o < 64; ++o) h2[o] = sB1[o];
#pragma unroll
  for (int c = 0; c < 64; ++c) {
    float v = h1[c];
#pragma unroll
    for (int o4 = 0; o4 < 16; ++o4) {
      float4 w = *(const float4*)&sW1[c * 64 + 4 * o4];
      h2[4 * o4 + 0] = fmaf(v, w.x, h2[4 * o4 + 0]);
      h2[4 * o4 + 1] = fmaf(v, w.y, h2[4 * o4 + 1]);
      h2[4 * o4 + 2] = fmaf(v, w.z, h2[4 * o4 + 2]);
      h2[4 * o4 + 3] = fmaf(v, w.w, h2[4 * o4 + 3]);
    }
  }
#pragma unroll
  for (int o4 = 0; o4 < 16; ++o4) {
    float4 o;
    o.x = fmaxf(h2[4 * o4 + 0], 0.f);
    o.y = fmaxf(h2[4 * o4 + 1], 0.f);
    o.z = fmaxf(h2[4 * o4 + 2], 0.f);
    o.w = fmaxf(h2[4 * o4 + 3], 0.f);
    *(float4*)&h[(long)p * 64 + 4 * o4] = o;
  }
}

// --------------------------------------------- A = feat @ W0[:64,:] + b0
__global__ __launch_bounds__(256) void k_precompA(
    const float* __restrict__ feat, const float* __restrict__ w,
    const float* __restrict__ b, float* __restrict__ A, int n) {
  __shared__ __align__(16) float sW[4352];
  __shared__ float sB[68];
  for (int i = threadIdx.x; i < 4352; i += 256) sW[i] = w[i];
  for (int i = threadIdx.x; i < 68; i += 256) sB[i] = b[i];
  __syncthreads();
  int p = blockIdx.x * 256 + threadIdx.x;
  if (p >= n) return;
  float acc[68];
#pragma unroll
  for (int o = 0; o < 68; ++o) acc[o] = sB[o];
#pragma unroll
  for (int c4 = 0; c4 < 16; ++c4) {
    float4 f = *(const float4*)&feat[(long)p * 64 + 4 * c4];
#pragma unroll
    for (int u = 0; u < 4; ++u) {
      float v = (u == 0) ? f.x : (u == 1) ? f.y : (u == 2) ? f.z : f.w;
      int c = 4 * c4 + u;
#pragma unroll
      for (int o4 = 0; o4 < 17; ++o4) {
        float4 wv = *(const float4*)&sW[c * 68 + 4 * o4];
        acc[4 * o4 + 0] = fmaf(v, wv.x, acc[4 * o4 + 0]);
        acc[4 * o4 + 1] = fmaf(v, wv.y, acc[4 * o4 + 1]);
        acc[4 * o4 + 2] = fmaf(v, wv.z, acc[4 * o4 + 2]);
        acc[4 * o4 + 3] = fmaf(v, wv.w, acc[4 * o4 + 3]);
      }
    }
  }
#pragma unroll
  for (int o4 = 0; o4 < 17; ++o4) {
    float4 o;
    o.x = acc[4 * o4 + 0]; o.y = acc[4 * o4 + 1];
    o.z = acc[4 * o4 + 2]; o.w = acc[4 * o4 + 3];
    *(float4*)&A[(long)p * 68 + 4 * o4] = o;
  }
}

// ---------------------------------------------------------------- zero sync
__global__ __launch_bounds__(64) void k_zero(u64* __restrict__ part, int n) {
  int i = threadIdx.x;
  if (i < n) part[i] = 0ull;
}

// ---------------------------------------------------------------- FPS L0
// Multi-block spin-synced FPS: NB blocks x 1024 threads = n threads, ONE
// point per thread (x,y,z,dr all registers -- no per-iteration data
// streaming at all). Per iteration each block publishes one u64 key
//   (tag:17 = iter | d2_bits:32 | (32767-idx):15)
// via device-scope relaxed atomic store; wave 0 of every block polls all NB
// slots (tag-in-word => data is its own flag, tags unique per iteration so
// no ABA; k_zero clears stale tags between graph replays), redundantly
// max-reduces -> everyone learns the same argmax. Tie-break = smallest
// index (max of 32767-idx), matching jnp.argmax. A monotone, NON-resetting
// poll budget guarantees termination even if co-residency were violated
// (NB=32 <= 256 CUs, so in practice it never trips).
template <int NB>
__global__ __launch_bounds__(1024) void k_fps_spin(
    const float* __restrict__ pos, int m, int* __restrict__ sel,
    u64* __restrict__ part) {
#pragma clang fp contract(off)
  __shared__ u64 wk[16];
  __shared__ int curS;
  const int t = threadIdx.x, lane = t & 63, wv = t >> 6;
  const int bid = blockIdx.x;
  const int idx = bid * 1024 + t;
  const float x0 = pos[3 * idx + 0];
  const float y0 = pos[3 * idx + 1];
  const float z0 = pos[3 * idx + 2];
  float dr = 3.402823466e38f;
  if (bid == 0 && t == 0) sel[0] = 0;
  int cur = 0;
  int budget = 0;  // total poll budget across ALL iterations (no reset)
  for (int i = 1; i < m; ++i) {
    float px = pos[3 * cur + 0], py = pos[3 * cur + 1], pz = pos[3 * cur + 2];
    float ax = x0 - px, ay = y0 - py, az = z0 - pz;
    float d = (ax * ax + ay * ay) + az * az;
    float nd = fminf(dr, d);
    dr = nd;
    u64 key = ((u64)(unsigned)i << 47) | ((u64)__float_as_uint(nd) << 15) |
              (unsigned)(32767 - idx);
    key = wave_max_u64(key);
    if (lane == 0) wk[wv] = key;
    __syncthreads();
    if (wv == 0) {
      u64 k = (lane < 16) ? wk[lane] : 0ull;
#pragma unroll
      for (int off = 8; off; off >>= 1) {
        u64 o = __shfl_xor(k, off, 64);
        if (o > k) k = o;
      }
      if (lane == 0)
        __hip_atomic_store(&part[bid], k, __ATOMIC_RELAXED,
                           __HIP_MEMORY_SCOPE_AGENT);
      // poll all NB slots until every tag == i (or budget exhausted)
      u64 got;
      for (;;) {
        got = __hip_atomic_load(&part[lane & (NB - 1)], __ATOMIC_RELAXED,
                                __HIP_MEMORY_SCOPE_AGENT);
        if (__ballot((unsigned)(got >> 47) == (unsigned)i) == ~0ull) break;
        if (++budget > (1 << 24)) break;  // fail visibly, never hang
      }
      got = wave_max_u64(got);
      if (lane == 0) {
        int c = 32767 - (int)(got & 0x7FFF);
        curS = c;
        if (bid == 0) sel[i] = c;
      }
    }
    __syncthreads();
    cur = curS;
  }
}

// ---------------------------------------------------------------- FPS L1/2
// Register-resident single-block variant (P<=32): xr/yr/dr = 3P <= 96 regs
// fits the 128-VGPR budget of 512-thread kernels. z in LDS. ~0.74 us/iter.
template <int P>
__global__ __launch_bounds__(512) void k_fps_reg(
    const float2* __restrict__ xy, const float* __restrict__ pos, int n,
    int m, int* __restrict__ sel) {
#pragma clang fp contract(off)
  __shared__ float zb[512 * P];
  __shared__ u64 wk[2][8];
  const int t = threadIdx.x, lane = t & 63, wv = t >> 6;
  float xr[P], yr[P], dr[P];
#pragma unroll
  for (int j = 0; j < P; ++j) {
    int idx = t + 512 * j;
    xr[j] = pos[3 * idx + 0];
    yr[j] = pos[3 * idx + 1];
    zb[idx] = pos[3 * idx + 2];
    dr[j] = 3.402823466e38f;
  }
  if (t == 0) sel[0] = 0;
  __syncthreads();
  int cur = 0;
  for (int i = 1; i < m; ++i) {
    float2 pxy = xy[cur];
    float pz = zb[cur];
    float px = pxy.x, py = pxy.y;
    float bv = -1.f;
    int bi = 0;
#pragma unroll
    for (int j = 0; j < P; ++j) {
      int idx = t + 512 * j;
      float ax = xr[j] - px, ay = yr[j] - py, az = zb[idx] - pz;
      float d = (ax * ax + ay * ay) + az * az;
      float nd = fminf(dr[j], d);
      dr[j] = nd;
      if (nd > bv) { bv = nd; bi = idx; }
    }
#pragma unroll
    for (int off = 32; off; off >>= 1) {
      float ov = __shfl_xor(bv, off, 64);
      int oi = __shfl_xor(bi, off, 64);
      if (ov > bv || (ov == bv && oi < bi)) { bv = ov; bi = oi; }
    }
    int par = i & 1;
    if (lane == 0)
      wk[par][wv] = ((u64)__float_as_uint(bv) << 32) | (unsigned)(~bi);
    __syncthreads();
    u64 bk = wk[par][0];
#pragma unroll
    for (int w = 1; w < 8; ++w) {
      u64 o = wk[par][w];
      if (o > bk) bk = o;
    }
    cur = (int)(~(unsigned)bk);
    if (t == 0) sel[i] = cur;
  }
}

// ---------------------------------------------------------------- gather
// Emits strided pos/norm plus packed float2 xy for the next FPS level.
__global__ __launch_bounds__(256) void k_gather(
    const float* __restrict__ pos, const float* __restrict__ nrm,
    const int* __restrict__ sel, int m, float* __restrict__ opos,
    float* __restrict__ onrm, float2* __restrict__ oxy) {
  int i = blockIdx.x * 256 + threadIdx.x;
  if (i >= m) return;
  int s = sel[i];
  float x = pos[3 * s + 0], y = pos[3 * s + 1], z = pos[3 * s + 2];
  opos[3 * i + 0] = x;
  opos[3 * i + 1] = y;
  opos[3 * i + 2] = z;
  oxy[i] = make_float2(x, y);
  onrm[3 * i + 0] = nrm[3 * s + 0];
  onrm[3 * i + 1] = nrm[3 * s + 1];
  onrm[3 * i + 2] = nrm[3 * s + 2];
}

// ---------------------------------------------------------------- conv
// Per block: 32 queries. Phase 1: exact (top-32 within radius) KNN via
// threshold-filtered candidate buffers. Phase 2: m1=relu(A_j+ppf@W0p),
// m2=relu(m1@W1+b1), max over neighbors, out=relu(agg@W2+b2).
__global__ __launch_bounds__(512) void k_conv(
    const float* __restrict__ qpos, const float* __restrict__ qnorm, int nq,
    const float* __restrict__ dpos, const float* __restrict__ dnorm, int n,
    const float* __restrict__ A, const float* __restrict__ w0p,
    const float* __restrict__ w1g, const float* __restrict__ b1g,
    const float* __restrict__ w2g, const float* __restrict__ b2g, float r2,
    float* __restrict__ xout) {
  __shared__ __align__(16) float smem[12288];  // tile(6144f) + cand(3072 u64) / later W1(4624f)+W2(4352f)
  __shared__ float aggS[QB][68];
  __shared__ int knnS[QB][32];
  __shared__ float qpS[QB][3], qnS[QB][3];
  __shared__ __align__(16) float w0pS[272];  // transposed [o][f]
  __shared__ float b1S[68], b2S[64];

  const int tid = threadIdx.x, lane = tid & 63, wv = tid >> 6;
  const int q0 = blockIdx.x * QB;
  float* tileS = smem;
  u64* cand = (u64*)&smem[6144];

  for (int i = tid; i < QB * 3; i += 512) {
    ((float*)qpS)[i] = qpos[q0 * 3 + i];
    ((float*)qnS)[i] = qnorm[q0 * 3 + i];
  }
  for (int i = tid; i < 272; i += 512) {
    int o = i >> 2, f = i & 3;
    w0pS[i] = w0p[f * 68 + o];
  }
  for (int i = tid; i < 68; i += 512) b1S[i] = b1g[i];
  for (int i = tid; i < 64; i += 512) b2S[i] = b2g[i];
  __syncthreads();

  // -------- KNN: each wave owns 4 queries --------
  float qx[4], qy[4], qz[4], thr[4];
  int cnt[4], tight[4];
#pragma unroll
  for (int qi = 0; qi < 4; ++qi) {
    int ql = wv * 4 + qi;
    qx[qi] = qpS[ql][0]; qy[qi] = qpS[ql][1]; qz[qi] = qpS[ql][2];
    thr[qi] = r2; cnt[qi] = 0; tight[qi] = 0;
  }
  const u64 lmask = (1ull << lane) - 1ull;
  for (int t0 = 0; t0 < n; t0 += TILE) {
    __syncthreads();
    for (int i = tid; i < TILE * 3; i += 512) tileS[i] = dpos[t0 * 3 + i];
    __syncthreads();
    for (int s = 0; s < TILE; s += 64) {
      int p = s + lane;
      float px = tileS[3 * p], py = tileS[3 * p + 1], pz = tileS[3 * p + 2];
      int gidx = t0 + p;
#pragma unroll
      for (int qi = 0; qi < 4; ++qi) {
        float d2;
        {
#pragma clang fp contract(off)
          float ax = px - qx[qi], ay = py - qy[qi], az = pz - qz[qi];
          d2 = (ax * ax + ay * ay) + az * az;
        }
        bool pred = tight[qi] ? (d2 < thr[qi]) : (d2 <= thr[qi]);
        u64 mask = __ballot(pred);
        if (mask) {
          int need = __popcll(mask);
          int base = (wv * 4 + qi) * CAP;
          if (cnt[qi] + need > CAP) {  // compact to 32 smallest, tighten thr
            u64 v0 = (lane < cnt[qi]) ? cand[base + lane] : ~0ull;
            u64 v1 = (lane + 64 < cnt[qi]) ? cand[base + lane + 64] : ~0ull;
            u64 keep = ~0ull, last = 0;
            for (int it = 0; it < 32; ++it) {
              u64 mloc = (v0 < v1) ? v0 : v1;
              u64 mn = wave_min_u64(mloc);
              if (lane == it) keep = mn;
              if (v0 == mn) v0 = ~0ull; else if (v1 == mn) v1 = ~0ull;
              last = mn;
            }
            if (lane < 32) cand[base + lane] = keep;
            cnt[qi] = 32;
            thr[qi] = __uint_as_float((unsigned)(last >> 32));
            tight[qi] = 1;
          }
          if (pred) {
            int slot = cnt[qi] + __popcll(mask & lmask);
            cand[base + slot] = ((u64)__float_as_uint(d2) << 32) | (unsigned)gidx;
          }
          cnt[qi] += need;
        }
      }
    }
  }
  // final exact selection (ascending (d2, idx)); pad with neighbor 0 (self)
#pragma unroll
  for (int qi = 0; qi < 4; ++qi) {
    int ql = wv * 4 + qi, base = ql * CAP, c = cnt[qi];
    int nout = (c < 32) ? c : 32;
    u64 v0 = (lane < c) ? cand[base + lane] : ~0ull;
    u64 v1 = (lane + 64 < c) ? cand[base + lane + 64] : ~0ull;
    int first = 0;
    for (int it = 0; it < 32; ++it) {
      u64 mloc = (v0 < v1) ? v0 : v1;
      u64 mn = wave_min_u64(mloc);
      int idx = (int)(mn & 0xffffffffu);
      if (it == 0) first = idx;
      int wr = (it < nout) ? idx : first;
      if (lane == it) knnS[ql][it] = wr;
      if (it < nout) {
        if (v0 == mn) v0 = ~0ull; else if (v1 == mn) v1 = ~0ull;
      }
    }
  }
  __syncthreads();
  for (int i = tid; i < 4624; i += 512) smem[i] = w1g[i];
  for (int i = tid; i < 4352; i += 512) smem[4624 + i] = w2g[i];
  __syncthreads();
  const float* W1s = smem;
  const float* W2s = smem + 4624;

  // -------- message MLP + max-agg: wave = 2 queries, lane = (query-half, k)
#pragma unroll 1
  for (int r = 0; r < 2; ++r) {
    const int h = lane >> 5;
    const int ql = r * 16 + wv * 2 + h;
    const int kk = lane & 31;
    const int j = knnS[ql][kk];
    const float qx_ = qpS[ql][0], qy_ = qpS[ql][1], qz_ = qpS[ql][2];
    float dx = dpos[3 * j + 0] - qx_;
    float dy = dpos[3 * j + 1] - qy_;
    float dz = dpos[3 * j + 2] - qz_;
    float f0 = sqrtf(dx * dx + dy * dy + dz * dz);
    float nix = qnS[ql][0], niy = qnS[ql][1], niz = qnS[ql][2];
    float njx = dnorm[3 * j + 0], njy = dnorm[3 * j + 1], njz = dnorm[3 * j + 2];
    float f1 = angf(nix, niy, niz, dx, dy, dz);
    float f2 = angf(njx, njy, njz, dx, dy, dz);
    float f3 = angf(nix, niy, niz, njx, njy, njz);
    const float* Arow = A + (long)j * 68;
    float m1[68];
#pragma unroll
    for (int o4 = 0; o4 < 17; ++o4) {
      float4 a = *(const float4*)&Arow[4 * o4];
#pragma unroll
      for (int u = 0; u < 4; ++u) {
        int o = 4 * o4 + u;
        float4 wf = *(const float4*)&w0pS[4 * o];
        float v = (u == 0) ? a.x : (u == 1) ? a.y : (u == 2) ? a.z : a.w;
        v = fmaf(f0, wf.x, v);
        v = fmaf(f1, wf.y, v);
        v = fmaf(f2, wf.z, v);
        v = fmaf(f3, wf.w, v);
        m1[o] = fmaxf(v, 0.f);
      }
    }
    float acc[68];
#pragma unroll
    for (int o = 0; o < 68; ++o) acc[o] = b1S[o];
#pragma unroll
    for (int c = 0; c < 68; ++c) {
      float mv = m1[c];
#pragma unroll
      for (int o4 = 0; o4 < 17; ++o4) {
        float4 wv4 = *(const float4*)&W1s[c * 68 + 4 * o4];
        acc[4 * o4 + 0] = fmaf(mv, wv4.x, acc[4 * o4 + 0]);
        acc[4 * o4 + 1] = fmaf(mv, wv4.y, acc[4 * o4 + 1]);
        acc[4 * o4 + 2] = fmaf(mv, wv4.z, acc[4 * o4 + 2]);
        acc[4 * o4 + 3] = fmaf(mv, wv4.w, acc[4 * o4 + 3]);
      }
    }
#pragma unroll
    for (int o = 0; o < 68; ++o) {
      float v = fmaxf(acc[o], 0.f);
#pragma unroll
      for (int off = 16; off; off >>= 1) v = fmaxf(v, __shfl_xor(v, off, 64));
      if (kk == 0) aggS[ql][o] = v;
    }
  }
  __syncthreads();
  // -------- nn2: out = relu(agg @ W2 + b2)
  {
    const int ql = tid >> 4;
    const int og = (tid & 15) * 4;
    float a0 = b2S[og + 0], a1 = b2S[og + 1], a2 = b2S[og + 2], a3 = b2S[og + 3];
#pragma unroll
    for (int c = 0; c < 68; ++c) {
      float av = aggS[ql][c];
      float4 wv4 = *(const float4*)&W2s[c * 64 + og];
      a0 = fmaf(av, wv4.x, a0);
      a1 = fmaf(av, wv4.y, a1);
      a2 = fmaf(av, wv4.z, a2);
      a3 = fmaf(av, wv4.w, a3);
    }
    float4 o;
    o.x = fmaxf(a0, 0.f); o.y = fmaxf(a1, 0.f);
    o.z = fmaxf(a2, 0.f); o.w = fmaxf(a3, 0.f);
    *(float4*)&xout[(long)(q0 + ql) * 64 + og] = o;
  }
}

// ---------------------------------------------------------------- final
__global__ __launch_bounds__(256) void k_final(
    const float* __restrict__ x3, const float* __restrict__ w0,
    const float* __restrict__ b0, const float* __restrict__ w1,
    const float* __restrict__ b1, float* __restrict__ out) {
  __shared__ float part[4][64];
  __shared__ float pooled[64];
  __shared__ float hS[64];
  int t = threadIdx.x, c = t & 63, g = t >> 6;
  float s = 0.f;
  for (int i = g; i < 4096; i += 4) s += x3[(long)i * 64 + c];
  part[g][c] = s;
  __syncthreads();
  if (t < 64)
    pooled[t] = (part[0][t] + part[1][t] + part[2][t] + part[3][t]) * (1.f / 4096.f);
  __syncthreads();
  if (t < 64) {
    float a = b0[t];
    for (int cc = 0; cc < 64; ++cc) a = fmaf(pooled[cc], w0[cc * 64 + t], a);
    hS[t] = fmaxf(a, 0.f);
  }
  __syncthreads();
  if (t < 2) {
    float a = b1[t];
    for (int cc = 0; cc < 64; ++cc) a = fmaf(hS[cc], w1[cc * 2 + t], a);
    out[t] = a;
  }
}

// ---------------------------------------------------------------- launch
extern "C" void kernel_launch(void* const* d_in, const int* in_sizes, int n_in,
                              void* d_out, int out_size, void* d_ws,
                              size_t ws_size, hipStream_t stream) {
  (void)in_sizes; (void)n_in; (void)out_size;
  const float* x     = (const float*)d_in[0];
  const float* pos   = (const float*)d_in[1];
  const float* nrm   = (const float*)d_in[2];
  const float* li_w0 = (const float*)d_in[3];
  const float* li_b0 = (const float*)d_in[4];
  const float* li_w1 = (const float*)d_in[5];
  const float* li_b1 = (const float*)d_in[6];
  const float* n1w0  = (const float*)d_in[7];   // [3][68][68]
  const float* n1b0  = (const float*)d_in[8];   // [3][68]
  const float* n1w1  = (const float*)d_in[9];   // [3][68][68]
  const float* n1b1  = (const float*)d_in[10];  // [3][68]
  const float* n2w   = (const float*)d_in[11];  // [3][68][64]
  const float* n2b   = (const float*)d_in[12];  // [3][64]
  const float* lo_w0 = (const float*)d_in[13];
  const float* lo_b0 = (const float*)d_in[14];
  const float* lo_w1 = (const float*)d_in[15];
  const float* lo_b1 = (const float*)d_in[16];
  float* out = (float*)d_out;

  char* ws = (char*)d_ws;
  size_t off = 0;
  auto alloc = [&](size_t nb) -> void* {
    void* p = (void*)(ws + off);
    off += nb;
    off = (off + 1023) & ~((size_t)1023);
    return p;
  };
  float* h    = (float*)alloc((size_t)32768 * 64 * 4);
  float* A0   = (float*)alloc((size_t)32768 * 68 * 4);
  u64*  partB = (u64*) alloc((size_t)64 * 8);
  int*   sel0 = (int*)  alloc((size_t)16384 * 4);
  float* pos1 = (float*)alloc((size_t)16384 * 3 * 4);
  float* nrm1 = (float*)alloc((size_t)16384 * 3 * 4);
  float2* xy1 = (float2*)alloc((size_t)16384 * 8);
  float* x1   = (float*)alloc((size_t)16384 * 64 * 4);
  float* A1   = (float*)alloc((size_t)16384 * 68 * 4);
  int*   sel1 = (int*)  alloc((size_t)8192 * 4);
  float* pos2 = (float*)alloc((size_t)8192 * 3 * 4);
  float* nrm2 = (float*)alloc((size_t)8192 * 3 * 4);
  float2* xy2 = (float2*)alloc((size_t)8192 * 8);
  float* x2   = (float*)alloc((size_t)8192 * 64 * 4);
  float* A2   = (float*)alloc((size_t)8192 * 68 * 4);
  int*   sel2 = (int*)  alloc((size_t)4096 * 4);
  float* pos3 = (float*)alloc((size_t)4096 * 3 * 4);
  float* nrm3 = (float*)alloc((size_t)4096 * 3 * 4);
  float2* xy3 = (float2*)alloc((size_t)4096 * 8);  // unused; keeps gather uniform
  float* x3   = (float*)alloc((size_t)4096 * 64 * 4);
  if (off > ws_size) return;  // workspace too small -> visible failure

  k_lin_in<<<128, 256, 0, stream>>>(x, li_w0, li_b0, li_w1, li_b1, h);
  k_precompA<<<128, 256, 0, stream>>>(h, n1w0, n1b0, A0, 32768);
  k_zero<<<1, 64, 0, stream>>>(partB, 64);
  k_fps_spin<32><<<32, 1024, 0, stream>>>(pos, 16384, sel0, partB);
  k_gather<<<64, 256, 0, stream>>>(pos, nrm, sel0, 16384, pos1, nrm1, xy1);
  k_conv<<<512, 512, 0, stream>>>(pos1, nrm1, 16384, pos, nrm, 32768, A0,
                                  n1w0 + 64 * 68, n1w1, n1b1, n2w, n2b, 4.0f,
                                  x1);
  k_fps_reg<32><<<1, 512, 0, stream>>>(xy1, pos1, 16384, 8192, sel1);
  k_gather<<<32, 256, 0, stream>>>(pos1, nrm1, sel1, 8192, pos2, nrm2, xy2);
  k_precompA<<<64, 256, 0, stream>>>(x1, n1w0 + 68 * 68, n1b0 + 68, A1, 16384);
  k_conv<<<256, 512, 0, stream>>>(pos2, nrm2, 8192, pos1, nrm1, 16384, A1,
                                  n1w0 + 68 * 68 + 64 * 68, n1w1 + 68 * 68,
                                  n1b1 + 68, n2w + 68 * 64, n2b + 64, 16.0f,
                                  x2);
  k_fps_reg<16><<<1, 512, 0, stream>>>(xy2, pos2, 8192, 4096, sel2);
  k_gather<<<16, 256, 0, stream>>>(pos2, nrm2, sel2, 4096, pos3, nrm3, xy3);
  k_precompA<<<32, 256, 0, stream>>>(x2, n1w0 + 2 * 68 * 68, n1b0 + 2 * 68, A2,
                                     8192);
  k_conv<<<128, 512, 0, stream>>>(pos3, nrm3, 4096, pos2, nrm2, 8192, A2,
                                  n1w0 + 2 * 68 * 68 + 64 * 68,
                                  n1w1 + 2 * 68 * 68, n1b1 + 2 * 68,
                                  n2w + 2 * 68 * 64, n2b + 2 * 64, 64.0f, x3);
  k_final<<<1, 256, 0, stream>>>(x3, lo_w0, lo_b0, lo_w1, lo_b1, out);
}

// Round 9
// 73195.740 us; speedup vs baseline: 2.4413x; 1.1742x over previous
//
#include <hip/hip_runtime.h>
#include <math.h>

typedef unsigned long long u64;

#define TILE 2048
#define CAP 96
#define QB 32

// ---------------------------------------------------------------- helpers
__device__ __forceinline__ u64 wave_min_u64(u64 v) {
#pragma unroll
  for (int off = 32; off; off >>= 1) {
    u64 o = __shfl_xor(v, off, 64);
    v = (o < v) ? o : v;
  }
  return v;
}

__device__ __forceinline__ u64 wave_max_u64(u64 v) {
#pragma unroll
  for (int off = 32; off; off >>= 1) {
    u64 o = __shfl_xor(v, off, 64);
    v = (o > v) ? o : v;
  }
  return v;
}

__device__ __forceinline__ float angf(float ax, float ay, float az,
                                      float bx, float by, float bz) {
  float cx = ay * bz - az * by;
  float cy = az * bx - ax * bz;
  float cz = ax * by - ay * bx;
  float cn = sqrtf(cx * cx + cy * cy + cz * cz);
  float dt = ax * bx + ay * by + az * bz;
  return atan2f(cn, dt);
}

// ---------------------------------------------------------------- lin_in
__global__ __launch_bounds__(256) void k_lin_in(
    const float* __restrict__ x, const float* __restrict__ w0,
    const float* __restrict__ b0, const float* __restrict__ w1,
    const float* __restrict__ b1, float* __restrict__ h) {
  __shared__ __align__(16) float sW0[1024];
  __shared__ __align__(16) float sW1[4096];
  __shared__ float sB0[64], sB1[64];
  for (int i = threadIdx.x; i < 1024; i += 256) sW0[i] = w0[i];
  for (int i = threadIdx.x; i < 4096; i += 256) sW1[i] = w1[i];
  if (threadIdx.x < 64) { sB0[threadIdx.x] = b0[threadIdx.x]; sB1[threadIdx.x] = b1[threadIdx.x]; }
  __syncthreads();
  int p = blockIdx.x * 256 + threadIdx.x;
  float h1[64];
#pragma unroll
  for (int o = 0; o < 64; ++o) h1[o] = sB0[o];
#pragma unroll
  for (int c4 = 0; c4 < 4; ++c4) {
    float4 xv = *(const float4*)&x[p * 16 + 4 * c4];
#pragma unroll
    for (int u = 0; u < 4; ++u) {
      float v = (u == 0) ? xv.x : (u == 1) ? xv.y : (u == 2) ? xv.z : xv.w;
      int c = 4 * c4 + u;
#pragma unroll
      for (int o4 = 0; o4 < 16; ++o4) {
        float4 w = *(const float4*)&sW0[c * 64 + 4 * o4];
        h1[4 * o4 + 0] = fmaf(v, w.x, h1[4 * o4 + 0]);
        h1[4 * o4 + 1] = fmaf(v, w.y, h1[4 * o4 + 1]);
        h1[4 * o4 + 2] = fmaf(v, w.z, h1[4 * o4 + 2]);
        h1[4 * o4 + 3] = fmaf(v, w.w, h1[4 * o4 + 3]);
      }
    }
  }
#pragma unroll
  for (int o = 0; o < 64; ++o) h1[o] = fmaxf(h1[o], 0.f);
  float h2[64];
#pragma unroll
  for (int o = 0; o < 64; ++o) h2[o] = sB1[o];
#pragma unroll
  for (int c = 0; c < 64; ++c) {
    float v = h1[c];
#pragma unroll
    for (int o4 = 0; o4 < 16; ++o4) {
      float4 w = *(const float4*)&sW1[c * 64 + 4 * o4];
      h2[4 * o4 + 0] = fmaf(v, w.x, h2[4 * o4 + 0]);
      h2[4 * o4 + 1] = fmaf(v, w.y, h2[4 * o4 + 1]);
      h2[4 * o4 + 2] = fmaf(v, w.z, h2[4 * o4 + 2]);
      h2[4 * o4 + 3] = fmaf(v, w.w, h2[4 * o4 + 3]);
    }
  }
#pragma unroll
  for (int o4 = 0; o4 < 16; ++o4) {
    float4 o;
    o.x = fmaxf(h2[4 * o4 + 0], 0.f);
    o.y = fmaxf(h2[4 * o4 + 1], 0.f);
    o.z = fmaxf(h2[4 * o4 + 2], 0.f);
    o.w = fmaxf(h2[4 * o4 + 3], 0.f);
    *(float4*)&h[(long)p * 64 + 4 * o4] = o;
  }
}

// --------------------------------------------- A = feat @ W0[:64,:] + b0
__global__ __launch_bounds__(256) void k_precompA(
    const float* __restrict__ feat, const float* __restrict__ w,
    const float* __restrict__ b, float* __restrict__ A, int n) {
  __shared__ __align__(16) float sW[4352];
  __shared__ float sB[68];
  for (int i = threadIdx.x; i < 4352; i += 256) sW[i] = w[i];
  for (int i = threadIdx.x; i < 68; i += 256) sB[i] = b[i];
  __syncthreads();
  int p = blockIdx.x * 256 + threadIdx.x;
  if (p >= n) return;
  float acc[68];
#pragma unroll
  for (int o = 0; o < 68; ++o) acc[o] = sB[o];
#pragma unroll
  for (int c4 = 0; c4 < 16; ++c4) {
    float4 f = *(const float4*)&feat[(long)p * 64 + 4 * c4];
#pragma unroll
    for (int u = 0; u < 4; ++u) {
      float v = (u == 0) ? f.x : (u == 1) ? f.y : (u == 2) ? f.z : f.w;
      int c = 4 * c4 + u;
#pragma unroll
      for (int o4 = 0; o4 < 17; ++o4) {
        float4 wv = *(const float4*)&sW[c * 68 + 4 * o4];
        acc[4 * o4 + 0] = fmaf(v, wv.x, acc[4 * o4 + 0]);
        acc[4 * o4 + 1] = fmaf(v, wv.y, acc[4 * o4 + 1]);
        acc[4 * o4 + 2] = fmaf(v, wv.z, acc[4 * o4 + 2]);
        acc[4 * o4 + 3] = fmaf(v, wv.w, acc[4 * o4 + 3]);
      }
    }
  }
#pragma unroll
  for (int o4 = 0; o4 < 17; ++o4) {
    float4 o;
    o.x = acc[4 * o4 + 0]; o.y = acc[4 * o4 + 1];
    o.z = acc[4 * o4 + 2]; o.w = acc[4 * o4 + 3];
    *(float4*)&A[(long)p * 68 + 4 * o4] = o;
  }
}

// ---------------------------------------------------------------- zero sync
__global__ __launch_bounds__(64) void k_zero(u64* __restrict__ part, int n) {
  int i = threadIdx.x;
  if (i < n) part[i] = 0ull;
}

// ---------------------------------------------------------------- FPS L0
// Multi-block spin-synced FPS: NB=8 blocks x 512 threads x P=8 points per
// thread; x,y,z,dr all in registers (32 regs, well under the 128-VGPR
// budget 512-thread kernels get). Per iteration each block publishes one
// u64 key (tag:17=iter | d2_bits:32 | (32767-idx):15) via device-scope
// relaxed atomic store; wave 0 of every block polls the NB slots and
// max-reduces -> everyone learns the argmax (smallest index on ties, as
// jnp.argmax). Two CORRECTNESS mechanisms:
//  * PARITY double-buffer part[2][NB]: iteration i uses parity i&1. A slot
//    of parity p is overwritten at i+2 only after ALL blocks passed poll
//    i+1, which requires all left poll i -- so no reader can miss its
//    value (fixes the R8 race that burned a 2.5s poll budget).
//  * Tag-in-word (data is its own flag, no fences); k_zero clears stale
//    tags between graph replays; monotone non-resetting poll budget
//    guarantees termination (fail visibly, never hang).
template <int NB, int NT, int P>
__global__ __launch_bounds__(NT) void k_fps_spin(
    const float* __restrict__ pos, int m, int* __restrict__ sel,
    u64* __restrict__ part) {
#pragma clang fp contract(off)
  constexpr int NW = NT / 64;
  __shared__ u64 wk[NW];
  __shared__ int curS;
  const int t = threadIdx.x, lane = t & 63, wv = t >> 6;
  const int bid = blockIdx.x;
  float xr[P], yr[P], zr[P], dr[P];
#pragma unroll
  for (int j = 0; j < P; ++j) {
    int idx = bid * (NT * P) + j * NT + t;
    xr[j] = pos[3 * idx + 0];
    yr[j] = pos[3 * idx + 1];
    zr[j] = pos[3 * idx + 2];
    dr[j] = 3.402823466e38f;
  }
  if (bid == 0 && t == 0) sel[0] = 0;
  int cur = 0;
  int budget = 0;  // total poll budget across ALL iterations (no reset)
  for (int i = 1; i < m; ++i) {
    float px = pos[3 * cur + 0], py = pos[3 * cur + 1], pz = pos[3 * cur + 2];
    u64 key = 0;
#pragma unroll
    for (int j = 0; j < P; ++j) {
      int idx = bid * (NT * P) + j * NT + t;
      float ax = xr[j] - px, ay = yr[j] - py, az = zr[j] - pz;
      float d = (ax * ax + ay * ay) + az * az;
      float nd = fminf(dr[j], d);
      dr[j] = nd;
      u64 kj = ((u64)__float_as_uint(nd) << 15) | (unsigned)(32767 - idx);
      if (kj > key) key = kj;
    }
    key |= ((u64)(unsigned)i << 47);
    key = wave_max_u64(key);
    if (lane == 0) wk[wv] = key;
    __syncthreads();  // barrier 1: wk complete
    if (wv == 0) {
      u64 k = (lane < NW) ? wk[lane] : 0ull;
#pragma unroll
      for (int off = NW / 2; off; off >>= 1) {
        u64 o = __shfl_xor(k, off, 64);
        if (o > k) k = o;
      }
      u64* slots = part + (size_t)(i & 1) * NB;  // parity buffer
      if (lane == 0)
        __hip_atomic_store(&slots[bid], k, __ATOMIC_RELAXED,
                           __HIP_MEMORY_SCOPE_AGENT);
      u64 got;
      for (;;) {
        got = __hip_atomic_load(&slots[lane & (NB - 1)], __ATOMIC_RELAXED,
                                __HIP_MEMORY_SCOPE_AGENT);
        if (__ballot((unsigned)(got >> 47) == (unsigned)i) == ~0ull) break;
        if (++budget > (1 << 24)) break;  // fail visibly, never hang
      }
      got = wave_max_u64(got);
      if (lane == 0) {
        int c = 32767 - (int)(got & 0x7FFF);
        curS = c;
        if (bid == 0) sel[i] = c;
      }
    }
    __syncthreads();  // barrier 2: curS ready
    cur = curS;
  }
}

// ---------------------------------------------------------------- FPS L1/2
// Register-resident single-block variant (P<=32): xr/yr/dr = 3P <= 96 regs
// fits the 128-VGPR budget of 512-thread kernels. z in LDS.
template <int P>
__global__ __launch_bounds__(512) void k_fps_reg(
    const float2* __restrict__ xy, const float* __restrict__ pos, int n,
    int m, int* __restrict__ sel) {
#pragma clang fp contract(off)
  __shared__ float zb[512 * P];
  __shared__ u64 wk[2][8];
  const int t = threadIdx.x, lane = t & 63, wv = t >> 6;
  float xr[P], yr[P], dr[P];
#pragma unroll
  for (int j = 0; j < P; ++j) {
    int idx = t + 512 * j;
    xr[j] = pos[3 * idx + 0];
    yr[j] = pos[3 * idx + 1];
    zb[idx] = pos[3 * idx + 2];
    dr[j] = 3.402823466e38f;
  }
  if (t == 0) sel[0] = 0;
  __syncthreads();
  int cur = 0;
  for (int i = 1; i < m; ++i) {
    float2 pxy = xy[cur];
    float pz = zb[cur];
    float px = pxy.x, py = pxy.y;
    float bv = -1.f;
    int bi = 0;
#pragma unroll
    for (int j = 0; j < P; ++j) {
      int idx = t + 512 * j;
      float ax = xr[j] - px, ay = yr[j] - py, az = zb[idx] - pz;
      float d = (ax * ax + ay * ay) + az * az;
      float nd = fminf(dr[j], d);
      dr[j] = nd;
      if (nd > bv) { bv = nd; bi = idx; }
    }
#pragma unroll
    for (int off = 32; off; off >>= 1) {
      float ov = __shfl_xor(bv, off, 64);
      int oi = __shfl_xor(bi, off, 64);
      if (ov > bv || (ov == bv && oi < bi)) { bv = ov; bi = oi; }
    }
    int par = i & 1;
    if (lane == 0)
      wk[par][wv] = ((u64)__float_as_uint(bv) << 32) | (unsigned)(~bi);
    __syncthreads();
    u64 bk = wk[par][0];
#pragma unroll
    for (int w = 1; w < 8; ++w) {
      u64 o = wk[par][w];
      if (o > bk) bk = o;
    }
    cur = (int)(~(unsigned)bk);
    if (t == 0) sel[i] = cur;
  }
}

// ---------------------------------------------------------------- gather
// Emits strided pos/norm plus packed float2 xy for the next FPS level.
__global__ __launch_bounds__(256) void k_gather(
    const float* __restrict__ pos, const float* __restrict__ nrm,
    const int* __restrict__ sel, int m, float* __restrict__ opos,
    float* __restrict__ onrm, float2* __restrict__ oxy) {
  int i = blockIdx.x * 256 + threadIdx.x;
  if (i >= m) return;
  int s = sel[i];
  float x = pos[3 * s + 0], y = pos[3 * s + 1], z = pos[3 * s + 2];
  opos[3 * i + 0] = x;
  opos[3 * i + 1] = y;
  opos[3 * i + 2] = z;
  oxy[i] = make_float2(x, y);
  onrm[3 * i + 0] = nrm[3 * s + 0];
  onrm[3 * i + 1] = nrm[3 * s + 1];
  onrm[3 * i + 2] = nrm[3 * s + 2];
}

// ---------------------------------------------------------------- conv
// Per block: 32 queries. Phase 1: exact (top-32 within radius) KNN via
// threshold-filtered candidate buffers. Phase 2: m1=relu(A_j+ppf@W0p),
// m2=relu(m1@W1+b1), max over neighbors, out=relu(agg@W2+b2).
__global__ __launch_bounds__(512) void k_conv(
    const float* __restrict__ qpos, const float* __restrict__ qnorm, int nq,
    const float* __restrict__ dpos, const float* __restrict__ dnorm, int n,
    const float* __restrict__ A, const float* __restrict__ w0p,
    const float* __restrict__ w1g, const float* __restrict__ b1g,
    const float* __restrict__ w2g, const float* __restrict__ b2g, float r2,
    float* __restrict__ xout) {
  __shared__ __align__(16) float smem[12288];  // tile(6144f) + cand(3072 u64) / later W1(4624f)+W2(4352f)
  __shared__ float aggS[QB][68];
  __shared__ int knnS[QB][32];
  __shared__ float qpS[QB][3], qnS[QB][3];
  __shared__ __align__(16) float w0pS[272];  // transposed [o][f]
  __shared__ float b1S[68], b2S[64];

  const int tid = threadIdx.x, lane = tid & 63, wv = tid >> 6;
  const int q0 = blockIdx.x * QB;
  float* tileS = smem;
  u64* cand = (u64*)&smem[6144];

  for (int i = tid; i < QB * 3; i += 512) {
    ((float*)qpS)[i] = qpos[q0 * 3 + i];
    ((float*)qnS)[i] = qnorm[q0 * 3 + i];
  }
  for (int i = tid; i < 272; i += 512) {
    int o = i >> 2, f = i & 3;
    w0pS[i] = w0p[f * 68 + o];
  }
  for (int i = tid; i < 68; i += 512) b1S[i] = b1g[i];
  for (int i = tid; i < 64; i += 512) b2S[i] = b2g[i];
  __syncthreads();

  // -------- KNN: each wave owns 4 queries --------
  float qx[4], qy[4], qz[4], thr[4];
  int cnt[4], tight[4];
#pragma unroll
  for (int qi = 0; qi < 4; ++qi) {
    int ql = wv * 4 + qi;
    qx[qi] = qpS[ql][0]; qy[qi] = qpS[ql][1]; qz[qi] = qpS[ql][2];
    thr[qi] = r2; cnt[qi] = 0; tight[qi] = 0;
  }
  const u64 lmask = (1ull << lane) - 1ull;
  for (int t0 = 0; t0 < n; t0 += TILE) {
    __syncthreads();
    for (int i = tid; i < TILE * 3; i += 512) tileS[i] = dpos[t0 * 3 + i];
    __syncthreads();
    for (int s = 0; s < TILE; s += 64) {
      int p = s + lane;
      float px = tileS[3 * p], py = tileS[3 * p + 1], pz = tileS[3 * p + 2];
      int gidx = t0 + p;
#pragma unroll
      for (int qi = 0; qi < 4; ++qi) {
        float d2;
        {
#pragma clang fp contract(off)
          float ax = px - qx[qi], ay = py - qy[qi], az = pz - qz[qi];
          d2 = (ax * ax + ay * ay) + az * az;
        }
        bool pred = tight[qi] ? (d2 < thr[qi]) : (d2 <= thr[qi]);
        u64 mask = __ballot(pred);
        if (mask) {
          int need = __popcll(mask);
          int base = (wv * 4 + qi) * CAP;
          if (cnt[qi] + need > CAP) {  // compact to 32 smallest, tighten thr
            u64 v0 = (lane < cnt[qi]) ? cand[base + lane] : ~0ull;
            u64 v1 = (lane + 64 < cnt[qi]) ? cand[base + lane + 64] : ~0ull;
            u64 keep = ~0ull, last = 0;
            for (int it = 0; it < 32; ++it) {
              u64 mloc = (v0 < v1) ? v0 : v1;
              u64 mn = wave_min_u64(mloc);
              if (lane == it) keep = mn;
              if (v0 == mn) v0 = ~0ull; else if (v1 == mn) v1 = ~0ull;
              last = mn;
            }
            if (lane < 32) cand[base + lane] = keep;
            cnt[qi] = 32;
            thr[qi] = __uint_as_float((unsigned)(last >> 32));
            tight[qi] = 1;
          }
          if (pred) {
            int slot = cnt[qi] + __popcll(mask & lmask);
            cand[base + slot] = ((u64)__float_as_uint(d2) << 32) | (unsigned)gidx;
          }
          cnt[qi] += need;
        }
      }
    }
  }
  // final exact selection (ascending (d2, idx)); pad with neighbor 0 (self)
#pragma unroll
  for (int qi = 0; qi < 4; ++qi) {
    int ql = wv * 4 + qi, base = ql * CAP, c = cnt[qi];
    int nout = (c < 32) ? c : 32;
    u64 v0 = (lane < c) ? cand[base + lane] : ~0ull;
    u64 v1 = (lane + 64 < c) ? cand[base + lane + 64] : ~0ull;
    int first = 0;
    for (int it = 0; it < 32; ++it) {
      u64 mloc = (v0 < v1) ? v0 : v1;
      u64 mn = wave_min_u64(mloc);
      int idx = (int)(mn & 0xffffffffu);
      if (it == 0) first = idx;
      int wr = (it < nout) ? idx : first;
      if (lane == it) knnS[ql][it] = wr;
      if (it < nout) {
        if (v0 == mn) v0 = ~0ull; else if (v1 == mn) v1 = ~0ull;
      }
    }
  }
  __syncthreads();
  for (int i = tid; i < 4624; i += 512) smem[i] = w1g[i];
  for (int i = tid; i < 4352; i += 512) smem[4624 + i] = w2g[i];
  __syncthreads();
  const float* W1s = smem;
  const float* W2s = smem + 4624;

  // -------- message MLP + max-agg: wave = 2 queries, lane = (query-half, k)
#pragma unroll 1
  for (int r = 0; r < 2; ++r) {
    const int h = lane >> 5;
    const int ql = r * 16 + wv * 2 + h;
    const int kk = lane & 31;
    const int j = knnS[ql][kk];
    const float qx_ = qpS[ql][0], qy_ = qpS[ql][1], qz_ = qpS[ql][2];
    float dx = dpos[3 * j + 0] - qx_;
    float dy = dpos[3 * j + 1] - qy_;
    float dz = dpos[3 * j + 2] - qz_;
    float f0 = sqrtf(dx * dx + dy * dy + dz * dz);
    float nix = qnS[ql][0], niy = qnS[ql][1], niz = qnS[ql][2];
    float njx = dnorm[3 * j + 0], njy = dnorm[3 * j + 1], njz = dnorm[3 * j + 2];
    float f1 = angf(nix, niy, niz, dx, dy, dz);
    float f2 = angf(njx, njy, njz, dx, dy, dz);
    float f3 = angf(nix, niy, niz, njx, njy, njz);
    const float* Arow = A + (long)j * 68;
    float m1[68];
#pragma unroll
    for (int o4 = 0; o4 < 17; ++o4) {
      float4 a = *(const float4*)&Arow[4 * o4];
#pragma unroll
      for (int u = 0; u < 4; ++u) {
        int o = 4 * o4 + u;
        float4 wf = *(const float4*)&w0pS[4 * o];
        float v = (u == 0) ? a.x : (u == 1) ? a.y : (u == 2) ? a.z : a.w;
        v = fmaf(f0, wf.x, v);
        v = fmaf(f1, wf.y, v);
        v = fmaf(f2, wf.z, v);
        v = fmaf(f3, wf.w, v);
        m1[o] = fmaxf(v, 0.f);
      }
    }
    float acc[68];
#pragma unroll
    for (int o = 0; o < 68; ++o) acc[o] = b1S[o];
#pragma unroll
    for (int c = 0; c < 68; ++c) {
      float mv = m1[c];
#pragma unroll
      for (int o4 = 0; o4 < 17; ++o4) {
        float4 wv4 = *(const float4*)&W1s[c * 68 + 4 * o4];
        acc[4 * o4 + 0] = fmaf(mv, wv4.x, acc[4 * o4 + 0]);
        acc[4 * o4 + 1] = fmaf(mv, wv4.y, acc[4 * o4 + 1]);
        acc[4 * o4 + 2] = fmaf(mv, wv4.z, acc[4 * o4 + 2]);
        acc[4 * o4 + 3] = fmaf(mv, wv4.w, acc[4 * o4 + 3]);
      }
    }
#pragma unroll
    for (int o = 0; o < 68; ++o) {
      float v = fmaxf(acc[o], 0.f);
#pragma unroll
      for (int off = 16; off; off >>= 1) v = fmaxf(v, __shfl_xor(v, off, 64));
      if (kk == 0) aggS[ql][o] = v;
    }
  }
  __syncthreads();
  // -------- nn2: out = relu(agg @ W2 + b2)
  {
    const int ql = tid >> 4;
    const int og = (tid & 15) * 4;
    float a0 = b2S[og + 0], a1 = b2S[og + 1], a2 = b2S[og + 2], a3 = b2S[og + 3];
#pragma unroll
    for (int c = 0; c < 68; ++c) {
      float av = aggS[ql][c];
      float4 wv4 = *(const float4*)&W2s[c * 64 + og];
      a0 = fmaf(av, wv4.x, a0);
      a1 = fmaf(av, wv4.y, a1);
      a2 = fmaf(av, wv4.z, a2);
      a3 = fmaf(av, wv4.w, a3);
    }
    float4 o;
    o.x = fmaxf(a0, 0.f); o.y = fmaxf(a1, 0.f);
    o.z = fmaxf(a2, 0.f); o.w = fmaxf(a3, 0.f);
    *(float4*)&xout[(long)(q0 + ql) * 64 + og] = o;
  }
}

// ---------------------------------------------------------------- final
__global__ __launch_bounds__(256) void k_final(
    const float* __restrict__ x3, const float* __restrict__ w0,
    const float* __restrict__ b0, const float* __restrict__ w1,
    const float* __restrict__ b1, float* __restrict__ out) {
  __shared__ float part[4][64];
  __shared__ float pooled[64];
  __shared__ float hS[64];
  int t = threadIdx.x, c = t & 63, g = t >> 6;
  float s = 0.f;
  for (int i = g; i < 4096; i += 4) s += x3[(long)i * 64 + c];
  part[g][c] = s;
  __syncthreads();
  if (t < 64)
    pooled[t] = (part[0][t] + part[1][t] + part[2][t] + part[3][t]) * (1.f / 4096.f);
  __syncthreads();
  if (t < 64) {
    float a = b0[t];
    for (int cc = 0; cc < 64; ++cc) a = fmaf(pooled[cc], w0[cc * 64 + t], a);
    hS[t] = fmaxf(a, 0.f);
  }
  __syncthreads();
  if (t < 2) {
    float a = b1[t];
    for (int cc = 0; cc < 64; ++cc) a = fmaf(hS[cc], w1[cc * 2 + t], a);
    out[t] = a;
  }
}

// ---------------------------------------------------------------- launch
extern "C" void kernel_launch(void* const* d_in, const int* in_sizes, int n_in,
                              void* d_out, int out_size, void* d_ws,
                              size_t ws_size, hipStream_t stream) {
  (void)in_sizes; (void)n_in; (void)out_size;
  const float* x     = (const float*)d_in[0];
  const float* pos   = (const float*)d_in[1];
  const float* nrm   = (const float*)d_in[2];
  const float* li_w0 = (const float*)d_in[3];
  const float* li_b0 = (const float*)d_in[4];
  const float* li_w1 = (const float*)d_in[5];
  const float* li_b1 = (const float*)d_in[6];
  const float* n1w0  = (const float*)d_in[7];   // [3][68][68]
  const float* n1b0  = (const float*)d_in[8];   // [3][68]
  const float* n1w1  = (const float*)d_in[9];   // [3][68][68]
  const float* n1b1  = (const float*)d_in[10];  // [3][68]
  const float* n2w   = (const float*)d_in[11];  // [3][68][64]
  const float* n2b   = (const float*)d_in[12];  // [3][64]
  const float* lo_w0 = (const float*)d_in[13];
  const float* lo_b0 = (const float*)d_in[14];
  const float* lo_w1 = (const float*)d_in[15];
  const float* lo_b1 = (const float*)d_in[16];
  float* out = (float*)d_out;

  char* ws = (char*)d_ws;
  size_t off = 0;
  auto alloc = [&](size_t nb) -> void* {
    void* p = (void*)(ws + off);
    off += nb;
    off = (off + 1023) & ~((size_t)1023);
    return p;
  };
  float* h    = (float*)alloc((size_t)32768 * 64 * 4);
  float* A0   = (float*)alloc((size_t)32768 * 68 * 4);
  u64*  partB = (u64*) alloc((size_t)64 * 8);
  int*   sel0 = (int*)  alloc((size_t)16384 * 4);
  float* pos1 = (float*)alloc((size_t)16384 * 3 * 4);
  float* nrm1 = (float*)alloc((size_t)16384 * 3 * 4);
  float2* xy1 = (float2*)alloc((size_t)16384 * 8);
  float* x1   = (float*)alloc((size_t)16384 * 64 * 4);
  float* A1   = (float*)alloc((size_t)16384 * 68 * 4);
  int*   sel1 = (int*)  alloc((size_t)8192 * 4);
  float* pos2 = (float*)alloc((size_t)8192 * 3 * 4);
  float* nrm2 = (float*)alloc((size_t)8192 * 3 * 4);
  float2* xy2 = (float2*)alloc((size_t)8192 * 8);
  float* x2   = (float*)alloc((size_t)8192 * 64 * 4);
  float* A2   = (float*)alloc((size_t)8192 * 68 * 4);
  int*   sel2 = (int*)  alloc((size_t)4096 * 4);
  float* pos3 = (float*)alloc((size_t)4096 * 3 * 4);
  float* nrm3 = (float*)alloc((size_t)4096 * 3 * 4);
  float2* xy3 = (float2*)alloc((size_t)4096 * 8);  // unused; keeps gather uniform
  float* x3   = (float*)alloc((size_t)4096 * 64 * 4);
  if (off > ws_size) return;  // workspace too small -> visible failure

  k_lin_in<<<128, 256, 0, stream>>>(x, li_w0, li_b0, li_w1, li_b1, h);
  k_precompA<<<128, 256, 0, stream>>>(h, n1w0, n1b0, A0, 32768);
  k_zero<<<1, 64, 0, stream>>>(partB, 64);
  k_fps_spin<8, 512, 8><<<8, 512, 0, stream>>>(pos, 16384, sel0, partB);
  k_gather<<<64, 256, 0, stream>>>(pos, nrm, sel0, 16384, pos1, nrm1, xy1);
  k_conv<<<512, 512, 0, stream>>>(pos1, nrm1, 16384, pos, nrm, 32768, A0,
                                  n1w0 + 64 * 68, n1w1, n1b1, n2w, n2b, 4.0f,
                                  x1);
  k_fps_reg<32><<<1, 512, 0, stream>>>(xy1, pos1, 16384, 8192, sel1);
  k_gather<<<32, 256, 0, stream>>>(pos1, nrm1, sel1, 8192, pos2, nrm2, xy2);
  k_precompA<<<64, 256, 0, stream>>>(x1, n1w0 + 68 * 68, n1b0 + 68, A1, 16384);
  k_conv<<<256, 512, 0, stream>>>(pos2, nrm2, 8192, pos1, nrm1, 16384, A1,
                                  n1w0 + 68 * 68 + 64 * 68, n1w1 + 68 * 68,
                                  n1b1 + 68, n2w + 68 * 64, n2b + 64, 16.0f,
                                  x2);
  k_fps_reg<16><<<1, 512, 0, stream>>>(xy2, pos2, 8192, 4096, sel2);
  k_gather<<<16, 256, 0, stream>>>(pos2, nrm2, sel2, 4096, pos3, nrm3, xy3);
  k_precompA<<<32, 256, 0, stream>>>(x2, n1w0 + 2 * 68 * 68, n1b0 + 2 * 68, A2,
                                     8192);
  k_conv<<<128, 512, 0, stream>>>(pos3, nrm3, 4096, pos2, nrm2, 8192, A2,
                                  n1w0 + 2 * 68 * 68 + 64 * 68,
                                  n1w1 + 2 * 68 * 68, n1b1 + 2 * 68,
                                  n2w + 2 * 68 * 64, n2b + 2 * 64, 64.0f, x3);
  k_final<<<1, 256, 0, stream>>>(x3, lo_w0, lo_b0, lo_w1, lo_b1, out);
}